// Round 4
// baseline (497.107 us; speedup 1.0000x reference)
//
#include <hip/hip_runtime.h>
#include <hip/hip_fp16.h>

// PolyConv: h = sum_k theta[k] * L_sym^k x,  L_sym = I - D^{-1/2} A D^{-1/2}
// N=100000 nodes, E=1600000 edges, F=64 features, 5 theta terms.
//
// Round 18: feature-chunked gather, done right. Tables are chunk-major
// [4][N+1][16] f16 planes (32B rows, 3.2MB/plane -> fully resident in a
// 4MB per-XCD L2). Unlike r16 (which kept 16B/lane and doubled iteration
// count), rows narrow AND edge-slots widen: 2 lanes/row, r=0..15 slots,
// two row-regs -> 32 edges/node/iter. Row-load instructions stay 1KB each
// and total inner-loop VALU per full pass equals the flat kernel; only
// prologue/csr cost x4. csr uses nontemporal loads and gout/h nontemporal
// stores so the streaming traffic can't evict the resident plane.
// f16 packed v_pk_add_f16 accumulate + zero-row trick (row N == 0) as r17.

constexpr int kF = 64;
constexpr int CH = 4;                 // feature chunks
constexpr int CF = 16;                // features per chunk (32B f16 rows)
constexpr int BSHIFT = 8;             // bucket = dst >> 8  (256 nodes/bucket)
constexpr int NB = 1 << BSHIFT;       // 256 nodes per bucket
constexpr int TILE = 2048;            // edges per phase-A block (4/thread)
constexpr int KMAX = 512;             // array bound for K (=391)

typedef unsigned nv4u __attribute__((ext_vector_type(4)));   // nontemporal-safe
typedef float    nv4f __attribute__((ext_vector_type(4)));

static __device__ __forceinline__ float hlo(unsigned u) {        // low f16 -> f32
    return __half2float(__ushort_as_half((unsigned short)(u & 0xffffu)));
}
static __device__ __forceinline__ float hhi(unsigned u) {        // high f16 -> f32
    return __half2float(__ushort_as_half((unsigned short)(u >> 16)));
}
static __device__ __forceinline__ unsigned pack2h(float a, float b) { // RNE
    return (unsigned)__half_as_ushort(__float2half_rn(a)) |
           ((unsigned)__half_as_ushort(__float2half_rn(b)) << 16);
}
static __device__ __forceinline__ unsigned padd2(unsigned a, unsigned b) {
    __half2 ha = *reinterpret_cast<__half2*>(&a);
    __half2 hb = *reinterpret_cast<__half2*>(&b);
    __half2 hc = __hadd2(ha, hb);                 // v_pk_add_f16
    return *reinterpret_cast<unsigned*>(&hc);
}
static __device__ __forceinline__ int ntl_i(const int* p) {      // streaming load
    return __builtin_nontemporal_load(p);
}

// Phase A: multisplit edges into K buckets (hist -> reserve -> direct global
// scatter with LDS cursors). Fused x (fp32) -> xb (f16, chunk-major planes).
__global__ void k_binA(const int* __restrict__ src, const int* __restrict__ dst,
                       unsigned* __restrict__ pairs, int* __restrict__ gcursor,
                       const float4* __restrict__ x4, uint4* __restrict__ xb4,
                       int n8, int N, int E, int K, int cap) {
    __shared__ int hist[KMAX];
    __shared__ int gb[KMAX];
    const int tid = threadIdx.x;        // blockDim = 512
    const long long tb = (long long)blockIdx.x * TILE;
    const int tcount = (int)min((long long)TILE, (long long)E - tb);
    const size_t ps4 = (size_t)(N + 1) * 2;      // plane stride in uint4

    // fused x -> f16 convert (disjoint slice per block), chunk-major out.
    // granule i = 8 floats = one (node nloc, chunk c, half dd) 16B cell.
    {
        int per = (n8 + gridDim.x - 1) / (int)gridDim.x;
        int b0 = blockIdx.x * per;
        int b1 = min(b0 + per, n8);
        for (int i = b0 + tid; i < b1; i += 512) {
            float4 a = x4[2 * i];
            float4 b = x4[2 * i + 1];
            uint4 o;
            o.x = pack2h(a.x, a.y);
            o.y = pack2h(a.z, a.w);
            o.z = pack2h(b.x, b.y);
            o.w = pack2h(b.z, b.w);
            int nloc = i >> 3, sub = i & 7;
            int c = sub >> 1, dd = sub & 1;
            xb4[(size_t)c * ps4 + (size_t)nloc * 2 + dd] = o;
        }
    }

    hist[tid] = 0;
    __syncthreads();
    int dc[4], sc[4];
    #pragma unroll
    for (int k = 0; k < 4; ++k) {
        int i = tid + k * 512;
        if (i < tcount) {
            dc[k] = dst[tb + i];
            sc[k] = src[tb + i];
            atomicAdd(&hist[dc[k] >> BSHIFT], 1);
        } else {
            dc[k] = -1;
        }
    }
    __syncthreads();
    int hv = hist[tid];
    gb[tid] = (tid < K && hv > 0) ? atomicAdd(&gcursor[tid], hv) : 0;
    hist[tid] = 0;                       // reuse as local cursor
    __syncthreads();
    #pragma unroll
    for (int k = 0; k < 4; ++k) {
        if (dc[k] >= 0) {
            int d = dc[k];
            int b = d >> BSHIFT;
            int pos = atomicAdd(&hist[b], 1);
            pairs[(size_t)b * cap + gb[b] + pos] =
                ((unsigned)(d & (NB - 1)) << 23) | (unsigned)sc[k];
        }
    }
}

// Phase B: one block (512 thr) per bucket of 256 nodes. In-kernel gbase
// scan, per-node counts -> LDS scan -> rp/dinv2/rdeg, scatter plain src ints
// to csr via absolute LDS cursors, then convert own bucket's xb->g0 slice
// (chunk-major planes) with LDS dinv. Zeroes g0's row N in every plane.
__global__ void k_binB(const unsigned* __restrict__ pairs, const int* __restrict__ gcursor,
                       int* __restrict__ rp, float* __restrict__ dinv2,
                       float* __restrict__ rdeg, int* __restrict__ csr,
                       const uint4* __restrict__ xb4, uint4* __restrict__ g04,
                       int N, int E, int K, int cap) {
    __shared__ int gsc[KMAX];
    __shared__ int cnt[NB];
    __shared__ int stmp[NB];
    __shared__ int cur[NB];
    __shared__ float sdinv[NB];
    const int b = blockIdx.x;
    const int tid = threadIdx.x;        // blockDim = 512
    const size_t ps4 = (size_t)(N + 1) * 2;      // plane stride in uint4

    if (b == 0 && tid < 8)               // zero row N of all 4 g0 planes
        g04[(size_t)(tid >> 1) * ps4 + (size_t)N * 2 + (tid & 1)] = make_uint4(0, 0, 0, 0);

    int gv = (tid < K) ? gcursor[tid] : 0;
    gsc[tid] = gv;
    __syncthreads();
    for (int o = 1; o < KMAX; o <<= 1) {
        int t = (tid >= o) ? gsc[tid - o] : 0;
        __syncthreads();
        gsc[tid] += t;
        __syncthreads();
    }
    const int ecnt = gcursor[b];
    const int base = gsc[b] - ecnt;     // inclusive - own = exclusive
    const unsigned* bp = pairs + (size_t)b * cap;

    if (tid < NB) cnt[tid] = 0;
    __syncthreads();
    for (int i = tid; i < ecnt; i += 512)
        atomicAdd(&cnt[bp[i] >> 23], 1);
    __syncthreads();
    int v = (tid < NB) ? cnt[tid] : 0;
    if (tid < NB) stmp[tid] = v;
    __syncthreads();
    for (int o = 1; o < NB; o <<= 1) {
        int t = (tid >= o && tid < NB) ? stmp[tid - o] : 0;
        __syncthreads();
        if (tid < NB) stmp[tid] += t;
        __syncthreads();
    }
    int node = (b << BSHIFT) + tid;
    if (tid < NB) {
        int abs0 = base + stmp[tid] - v;            // exclusive, absolute
        cur[tid] = abs0;
        float d = fmaxf((float)v, 1.0f);
        sdinv[tid] = rsqrtf(d);
        if (node < N) {
            rp[node] = abs0;
            dinv2[node] = 1.0f / d;
            rdeg[node]  = sqrtf(d);
        }
    }
    if (b == K - 1 && tid == 0) rp[N] = E;
    __syncthreads();
    for (int i = tid; i < ecnt; i += 512) {
        unsigned p = bp[i];
        int pos = atomicAdd(&cur[p >> 23], 1);      // absolute csr index
        csr[pos] = (int)(p & 0x7FFFFFu);
    }
    // fused g0 = f16(dinv * x) for this bucket's nodes, per chunk plane
    const int nbase = b << BSHIFT;
    const int nn = min(NB, N - nbase);
    for (int c = 0; c < CH; ++c) {
        const uint4* xp = xb4 + (size_t)c * ps4 + (size_t)nbase * 2;
        uint4*       gp = g04 + (size_t)c * ps4 + (size_t)nbase * 2;
        for (int q = tid; q < nn * 2; q += 512) {
            float di = sdinv[q >> 1];
            uint4 xv = xp[q];
            uint4 o;
            o.x = pack2h(di * hlo(xv.x), di * hhi(xv.x));
            o.y = pack2h(di * hlo(xv.y), di * hhi(xv.y));
            o.z = pack2h(di * hlo(xv.z), di * hhi(xv.z));
            o.w = pack2h(di * hlo(xv.w), di * hhi(xv.w));
            gp[q] = o;
        }
    }
}

// Chunk-phased gather. Grid = CH * cblocks; chunk-major block order keeps
// the active 3.2MB gin plane L2-resident. Per wave: 2 nodes (half=l>>5),
// 32 edge slots/node/iter: r=(l>>1)&15 slot, c=l&1 halves a 32B row,
// row-regs rc1 (slot r) and rc2 (slot r+16). Depth-2 software pipeline.
// Packed v_pk_add_f16 accumulate; OOB slots gather zero row n.
// Butterfly ^2,^4,^8,^16 -> lanes {0,1,32,33}.
// !LAST: gout_plane[node] = f16(gin_plane[node] - dinv2*acc)  (nt store)
//  LAST: h[node, chunk*16 + c*8 ..] = t0*xb + rd*(t1*g1+t2*g2+t3*gin+t4*g4)
template <bool LAST>
__global__ void k_gather(const int* __restrict__ rp, const int* __restrict__ csr,
                         const unsigned short* __restrict__ gin,
                         const float* __restrict__ dinv2,
                         unsigned short* __restrict__ gout,
                         const unsigned short* __restrict__ xb,
                         const unsigned short* __restrict__ g1t,
                         const unsigned short* __restrict__ g2t,
                         const float* __restrict__ rdeg,
                         float* __restrict__ h, int n, int cblocks,
                         float t0, float t1, float t2, float t3, float t4) {
    const size_t ps = (size_t)(n + 1) * CF;        // plane stride (ushorts)
    if (!LAST && blockIdx.x == 0 && threadIdx.x < 8) { // zero row n, 4 planes
        int p = threadIdx.x >> 1, cc = threadIdx.x & 1;
        *(uint4*)(gout + (size_t)p * ps + (size_t)n * CF + cc * 8) = make_uint4(0, 0, 0, 0);
    }

    const int chunk = blockIdx.x / cblocks;
    const int bidx  = blockIdx.x - chunk * cblocks;
    const int wid   = bidx * 4 + (threadIdx.x >> 6);
    const int lane  = threadIdx.x & 63;
    const int half  = lane >> 5;
    const int r     = (lane >> 1) & 15;
    const int c     = lane & 1;
    const int node  = wid * 2 + half;
    if (wid * 2 >= n) return;
    bool valid = node < n;
    int beg = valid ? rp[node] : 0;
    int end = valid ? rp[node + 1] : 0;
    int len = end - beg;
    int olen = __shfl_xor(len, 32, 64);
    int mlen = (len > olen) ? len : olen;   // pair max -> uniform trip count

    const unsigned short* gp = gin + (size_t)chunk * ps;

    unsigned acc[4] = {0u, 0u, 0u, 0u};     // packed f16 pairs (8 f16)

    // pipeline state: current rows (in flight), next row indices
    uint4 rc1 = make_uint4(0, 0, 0, 0), rc2 = make_uint4(0, 0, 0, 0);
    int sn1 = n, sn2 = n;
    if (mlen > 0) {
        int j1 = beg + r, j2 = j1 + 16;
        bool o1 = j1 < end, o2 = j2 < end;
        int s1 = ntl_i(csr + (o1 ? j1 : 0)); s1 = o1 ? s1 : n;
        int s2 = ntl_i(csr + (o2 ? j2 : 0)); s2 = o2 ? s2 : n;
        rc1 = *(const uint4*)(gp + ((size_t)s1 << 4) + (c << 3));
        rc2 = *(const uint4*)(gp + ((size_t)s2 << 4) + (c << 3));
        int j1b = beg + 32 + r, j2b = j1b + 16;
        bool vb = 32 < mlen;
        bool b1 = vb && (j1b < end), b2 = vb && (j2b < end);
        sn1 = ntl_i(csr + (b1 ? j1b : 0)); sn1 = b1 ? sn1 : n;
        sn2 = ntl_i(csr + (b2 ? j2b : 0)); sn2 = b2 ? sn2 : n;
    }
    for (int i = 0; i < mlen; i += 32) {
        // issue NEXT iteration's rows (independent of rc1/rc2 wait)
        uint4 rn1 = *(const uint4*)(gp + ((size_t)sn1 << 4) + (c << 3));
        uint4 rn2 = *(const uint4*)(gp + ((size_t)sn2 << 4) + (c << 3));
        // prefetch csr two iterations ahead
        int j1n = beg + i + 64 + r, j2n = j1n + 16;
        bool vn = (i + 64) < mlen;
        bool t1c = vn && (j1n < end), t2c = vn && (j2n < end);
        int st1 = ntl_i(csr + (t1c ? j1n : 0)); st1 = t1c ? st1 : n;
        int st2 = ntl_i(csr + (t2c ? j2n : 0)); st2 = t2c ? st2 : n;
        // accumulate CURRENT rows (packed f16)
        acc[0] = padd2(acc[0], rc1.x); acc[1] = padd2(acc[1], rc1.y);
        acc[2] = padd2(acc[2], rc1.z); acc[3] = padd2(acc[3], rc1.w);
        acc[0] = padd2(acc[0], rc2.x); acc[1] = padd2(acc[1], rc2.y);
        acc[2] = padd2(acc[2], rc2.z); acc[3] = padd2(acc[3], rc2.w);
        // rotate pipeline
        rc1 = rn1; rc2 = rn2;
        sn1 = st1; sn2 = st2;
    }
    #pragma unroll
    for (int m = 2; m <= 16; m <<= 1) {
        #pragma unroll
        for (int i = 0; i < 4; ++i)
            acc[i] = padd2(acc[i], __shfl_xor(acc[i], m, 64));
    }

    if (r == 0 && valid) {                   // lanes 0,1 and 32,33
        size_t off = (size_t)chunk * ps + ((size_t)node << 4) + (c << 3);
        uint4 rr = *(const uint4*)(gin + off);
        float d2 = dinv2[node];
        float v[8];
        v[0] = hlo(rr.x) - d2 * hlo(acc[0]); v[1] = hhi(rr.x) - d2 * hhi(acc[0]);
        v[2] = hlo(rr.y) - d2 * hlo(acc[1]); v[3] = hhi(rr.y) - d2 * hhi(acc[1]);
        v[4] = hlo(rr.z) - d2 * hlo(acc[2]); v[5] = hhi(rr.z) - d2 * hhi(acc[2]);
        v[6] = hlo(rr.w) - d2 * hlo(acc[3]); v[7] = hhi(rr.w) - d2 * hhi(acc[3]);
        if (!LAST) {
            nv4u o;
            o.x = pack2h(v[0], v[1]);
            o.y = pack2h(v[2], v[3]);
            o.z = pack2h(v[4], v[5]);
            o.w = pack2h(v[6], v[7]);
            __builtin_nontemporal_store(o, (nv4u*)(gout + off));
        } else {
            nv4u xv = __builtin_nontemporal_load((const nv4u*)(xb + off));
            nv4u a  = __builtin_nontemporal_load((const nv4u*)(g1t + off));
            nv4u b  = __builtin_nontemporal_load((const nv4u*)(g2t + off));
            float rd = rdeg[node];
            float s1 = rd * t1, s2 = rd * t2, s3 = rd * t3, s4 = rd * t4;
            nv4f h0, h1;
            h0.x = t0 * hlo(xv.x) + s1 * hlo(a.x) + s2 * hlo(b.x) + s3 * hlo(rr.x) + s4 * v[0];
            h0.y = t0 * hhi(xv.x) + s1 * hhi(a.x) + s2 * hhi(b.x) + s3 * hhi(rr.x) + s4 * v[1];
            h0.z = t0 * hlo(xv.y) + s1 * hlo(a.y) + s2 * hlo(b.y) + s3 * hlo(rr.y) + s4 * v[2];
            h0.w = t0 * hhi(xv.y) + s1 * hhi(a.y) + s2 * hhi(b.y) + s3 * hhi(rr.y) + s4 * v[3];
            h1.x = t0 * hlo(xv.z) + s1 * hlo(a.z) + s2 * hlo(b.z) + s3 * hlo(rr.z) + s4 * v[4];
            h1.y = t0 * hhi(xv.z) + s1 * hhi(a.z) + s2 * hhi(b.z) + s3 * hhi(rr.z) + s4 * v[5];
            h1.z = t0 * hlo(xv.w) + s1 * hlo(a.w) + s2 * hlo(b.w) + s3 * hlo(rr.w) + s4 * v[6];
            h1.w = t0 * hhi(xv.w) + s1 * hhi(a.w) + s2 * hhi(b.w) + s3 * hhi(rr.w) + s4 * v[7];
            size_t hoff = (size_t)node * kF + chunk * CF + (c << 3);
            __builtin_nontemporal_store(h0, (nv4f*)(h + hoff));
            __builtin_nontemporal_store(h1, (nv4f*)(h + hoff + 4));
        }
    }
}

extern "C" void kernel_launch(void* const* d_in, const int* in_sizes, int n_in,
                              void* d_out, int out_size, void* d_ws, size_t ws_size,
                              hipStream_t stream) {
    const float* x  = (const float*)d_in[0];
    const int*   ei = (const int*)d_in[1];   // edge_index [2, E] row-major
    const int N = in_sizes[0] / kF;
    const int E = in_sizes[1] / 2;
    const int* src = ei;
    const int* dst = ei + E;
    float* h = (float*)d_out;

    const int K = (N + NB - 1) >> BSHIFT;         // 391 buckets (K <= KMAX)
    const int cap = 2 * ((E + K - 1) / K);        // per-bucket capacity

    // workspace (~77 MB): gcursor | rp | dinv2 | rdeg | csr | xb | g0 |
    // g1 (aliases pairs: g1 first written in gather pass 1; pairs dead
    // after binB) | g2 | g3.  Feature tables are [4][N+1][16] f16 planes
    // (row N of each plane = zeros).
    char* ws = (char*)d_ws;
    size_t off = 0;
    auto carve = [&](size_t bytes) {
        void* p = ws + off;
        off = (off + bytes + 511) & ~(size_t)511;
        return p;
    };
    size_t gbytes = (size_t)CH * (N + 1) * CF * 2;    // = (N+1)*128 bytes
    int*            gcursor = (int*)carve((size_t)K * 4);
    int*            rp      = (int*)carve((size_t)(N + 1) * 4);
    float*          dinv2   = (float*)carve((size_t)N * 4);
    float*          rdeg    = (float*)carve((size_t)N * 4);
    int*            csr     = (int*)carve((size_t)E * 4);
    unsigned short* xb      = (unsigned short*)carve(gbytes);
    unsigned short* g0      = (unsigned short*)carve(gbytes);
    size_t pbytes = (size_t)K * cap * 4;
    unsigned short* g1      = (unsigned short*)carve(gbytes > pbytes ? gbytes : pbytes);
    unsigned short* g2      = (unsigned short*)carve(gbytes);
    unsigned short* g3      = (unsigned short*)carve(gbytes);
    unsigned*       pairs   = (unsigned*)g1;       // alias (see above)

    const float theta[5] = {0.6f, -0.4f, 0.3f, -0.2f, 0.1f};
    const int n8 = N * kF / 8;

    // ---- CSR build (multisplit) with fused x->f16 convert and g0 ----
    hipMemsetAsync(gcursor, 0, (size_t)K * 4, stream);
    k_binA<<<(E + TILE - 1) / TILE, 512, 0, stream>>>(src, dst, pairs, gcursor,
                                                      (const float4*)x, (uint4*)xb,
                                                      n8, N, E, K, cap);
    k_binB<<<K, 512, 0, stream>>>(pairs, gcursor, rp, dinv2, rdeg, csr,
                                  (const uint4*)xb, (uint4*)g0, N, E, K, cap);

    // ---- 4 chunk-phased gather passes; pass 4 fuses the h-combine ----
    const int nwaves = (N + 1) / 2;                // 2 nodes per wave
    const int cblocks = (nwaves + 3) / 4;          // 4 waves per 256-thread block
    const int gblocks = CH * cblocks;
    k_gather<false><<<gblocks, 256, 0, stream>>>(rp, csr, g0, dinv2, g1,
                                                 nullptr, nullptr, nullptr, nullptr,
                                                 nullptr, N, cblocks, 0, 0, 0, 0, 0);
    k_gather<false><<<gblocks, 256, 0, stream>>>(rp, csr, g1, dinv2, g2,
                                                 nullptr, nullptr, nullptr, nullptr,
                                                 nullptr, N, cblocks, 0, 0, 0, 0, 0);
    k_gather<false><<<gblocks, 256, 0, stream>>>(rp, csr, g2, dinv2, g3,
                                                 nullptr, nullptr, nullptr, nullptr,
                                                 nullptr, N, cblocks, 0, 0, 0, 0, 0);
    k_gather<true><<<gblocks, 256, 0, stream>>>(rp, csr, g3, dinv2, nullptr,
                                                xb, g1, g2, rdeg, h, N, cblocks,
                                                theta[0], theta[1], theta[2],
                                                theta[3], theta[4]);
}

// Round 5
// 429.007 us; speedup vs baseline: 1.1587x; 1.1587x over previous
//
#include <hip/hip_runtime.h>
#include <hip/hip_fp16.h>

// PolyConv: h = sum_k theta[k] * L_sym^k x,  L_sym = I - D^{-1/2} A D^{-1/2}
// N=100000 nodes, E=1600000 edges, F=64 features, 5 theta terms.
//
// Round 19: gather kernels reverted to r17 flat form (244.5us; chunking
// r16/r18 lost 4x on per-wave fixed cost). CSR build rebuilt as 3 kernels
// with ONE edge scatter instead of two:
//   k_hist:    deg[dst]++ (global atomic) + btot[bucket]++ (LDS hist ->
//              1 atomic/bucket/block) + fused x->f16 convert.
//   k_scan:    per-bucket block: KMAX scan of btot (LDS), 256-node local
//              scan of deg -> rp/cur/dinv2/rdeg + fused g0 convert.
//   k_scatter: pos = atomicAdd(cur[dst]); csr[pos] = src  (the single
//              random 4B scatter; was done TWICE before via pairs+csr).
// No pairs array at all (frees the aliasing hazards).

constexpr int kF = 64;
constexpr int BSHIFT = 8;             // bucket = dst >> 8  (256 nodes/bucket)
constexpr int NB = 1 << BSHIFT;       // 256 nodes per bucket
constexpr int TILE = 2048;            // edges per block (4/thread)
constexpr int KMAX = 512;             // array bound for K (=391)

typedef unsigned nv4u __attribute__((ext_vector_type(4)));   // nontemporal-safe
typedef float    nv4f __attribute__((ext_vector_type(4)));

static __device__ __forceinline__ float hlo(unsigned u) {        // low f16 -> f32
    return __half2float(__ushort_as_half((unsigned short)(u & 0xffffu)));
}
static __device__ __forceinline__ float hhi(unsigned u) {        // high f16 -> f32
    return __half2float(__ushort_as_half((unsigned short)(u >> 16)));
}
static __device__ __forceinline__ unsigned pack2h(float a, float b) { // RNE
    return (unsigned)__half_as_ushort(__float2half_rn(a)) |
           ((unsigned)__half_as_ushort(__float2half_rn(b)) << 16);
}
static __device__ __forceinline__ unsigned padd2(unsigned a, unsigned b) {
    __half2 ha = *reinterpret_cast<__half2*>(&a);
    __half2 hb = *reinterpret_cast<__half2*>(&b);
    __half2 hc = __hadd2(ha, hb);                 // v_pk_add_f16
    return *reinterpret_cast<unsigned*>(&hc);
}

// k1: degree histogram (global atomics, low contention: avg 16/node) +
// bucket totals via LDS histogram (one global atomic per bucket per block)
// + fused x (fp32) -> xb (f16) conversion.
__global__ void k_hist(const int* __restrict__ dst, int* __restrict__ deg,
                       int* __restrict__ btot,
                       const float4* __restrict__ x4, uint4* __restrict__ xb4,
                       int n8, int E) {
    __shared__ int hist[KMAX];
    const int tid = threadIdx.x;        // blockDim = 512
    const long long tb = (long long)blockIdx.x * TILE;
    const int tcount = (int)min((long long)TILE, (long long)E - tb);

    // fused x -> f16 convert (disjoint slice per block)
    {
        int per = (n8 + gridDim.x - 1) / (int)gridDim.x;
        int b0 = blockIdx.x * per;
        int b1 = min(b0 + per, n8);
        for (int i = b0 + tid; i < b1; i += 512) {
            float4 a = x4[2 * i];
            float4 b = x4[2 * i + 1];
            uint4 o;
            o.x = pack2h(a.x, a.y);
            o.y = pack2h(a.z, a.w);
            o.z = pack2h(b.x, b.y);
            o.w = pack2h(b.z, b.w);
            xb4[i] = o;
        }
    }

    hist[tid] = 0;
    __syncthreads();
    #pragma unroll
    for (int k = 0; k < 4; ++k) {
        int i = tid + k * 512;
        if (i < tcount) {
            int d = __builtin_nontemporal_load(dst + tb + i);
            atomicAdd(&deg[d], 1);
            atomicAdd(&hist[d >> BSHIFT], 1);
        }
    }
    __syncthreads();
    int hv = hist[tid];
    if (hv > 0) atomicAdd(&btot[tid], hv);
}

// k2: one block (512 thr) per bucket of 256 nodes. KMAX scan of btot in
// LDS -> bucket base; local scan of deg -> rp/cur/dinv2/rdeg; fused
// g0 = f16(dinv * x) conversion; zero row N of g0.
__global__ void k_scan(const int* __restrict__ btot, const int* __restrict__ deg,
                       int* __restrict__ rp, int* __restrict__ cur,
                       float* __restrict__ dinv2, float* __restrict__ rdeg,
                       const uint4* __restrict__ xb, uint4* __restrict__ g0,
                       int N, int E, int K) {
    __shared__ int gsc[KMAX];
    __shared__ int stmp[NB];
    __shared__ float sdinv[NB];
    const int b = blockIdx.x;
    const int tid = threadIdx.x;        // blockDim = 512

    if (b == 0 && tid < 8)               // zero row N of g0
        g0[((size_t)N << 3) + tid] = make_uint4(0, 0, 0, 0);

    gsc[tid] = (tid < K) ? btot[tid] : 0;
    __syncthreads();
    for (int o = 1; o < KMAX; o <<= 1) {
        int t = (tid >= o) ? gsc[tid - o] : 0;
        __syncthreads();
        gsc[tid] += t;
        __syncthreads();
    }
    const int base = gsc[b] - btot[b];  // exclusive bucket base

    int node = (b << BSHIFT) + tid;
    int v = (tid < NB && node < N) ? deg[node] : 0;
    if (tid < NB) stmp[tid] = v;
    __syncthreads();
    for (int o = 1; o < NB; o <<= 1) {
        int t = (tid >= o && tid < NB) ? stmp[tid - o] : 0;
        __syncthreads();
        if (tid < NB) stmp[tid] += t;
        __syncthreads();
    }
    if (tid < NB) {
        int abs0 = base + stmp[tid] - v;            // exclusive, absolute
        float d = fmaxf((float)v, 1.0f);
        sdinv[tid] = rsqrtf(d);
        if (node < N) {
            rp[node]  = abs0;
            cur[node] = abs0;
            dinv2[node] = 1.0f / d;
            rdeg[node]  = sqrtf(d);
        }
    }
    if (b == K - 1 && tid == 0) rp[N] = E;
    __syncthreads();
    // fused g0 = f16(dinv * x) for this bucket's nodes (streaming 32KB)
    const int nbase = b << BSHIFT;
    const int qmax = min(NB, N - nbase) << 3;       // 8 uint4 per node
    const uint4* xbp = xb + ((size_t)nbase << 3);
    uint4* g0p = g0 + ((size_t)nbase << 3);
    for (int q = tid; q < qmax; q += 512) {
        float di = sdinv[q >> 3];
        uint4 xv = xbp[q];
        uint4 o;
        o.x = pack2h(di * hlo(xv.x), di * hhi(xv.x));
        o.y = pack2h(di * hlo(xv.y), di * hhi(xv.y));
        o.z = pack2h(di * hlo(xv.z), di * hhi(xv.z));
        o.w = pack2h(di * hlo(xv.w), di * hhi(xv.w));
        g0p[q] = o;
    }
}

// k3: the single edge scatter. pos = cur[dst]++ (device atomic, avg 16
// hits/counter); csr[pos] = src (nt store; random 4B, merged in L2).
__global__ void k_scatter(const int* __restrict__ src, const int* __restrict__ dst,
                          int* __restrict__ cur, int* __restrict__ csr, int E) {
    const int tid = threadIdx.x;        // blockDim = 512
    const long long tb = (long long)blockIdx.x * TILE;
    const int tcount = (int)min((long long)TILE, (long long)E - tb);
    #pragma unroll
    for (int k = 0; k < 4; ++k) {
        int i = tid + k * 512;
        if (i < tcount) {
            int d = __builtin_nontemporal_load(dst + tb + i);
            int s = __builtin_nontemporal_load(src + tb + i);
            int pos = atomicAdd(&cur[d], 1);
            __builtin_nontemporal_store(s, csr + pos);
        }
    }
}

// TWO nodes per wave, f16 feature tables (128B rows), depth-2 software
// pipeline (csr one iter ahead, rows issued before accumulate). Lane l:
// half = l>>5, r = (l>>3)&3, c = l&7. Packed v_pk_add_f16 accumulate;
// OOB slots gather the zero row at index n (no weight selects).
// Butterfly ^8,^16 -> lanes {0..7,32..39}.
// !LAST epilogue: gout[d] = f16(gin[d] - dinv2[d]*acc)  (+ zero row N)
//  LAST epilogue: h[d] = t0*xb[d] + rdeg[d]*(t1*g1+t2*g2+t3*gin+t4*g4),
//                 g4 = gin[d] - dinv2[d]*acc computed in-register.
template <bool LAST>
__global__ void k_gather(const int* __restrict__ rp, const int* __restrict__ csr,
                         const unsigned short* __restrict__ gin,
                         const float* __restrict__ dinv2,
                         unsigned short* __restrict__ gout,
                         const unsigned short* __restrict__ xb,
                         const unsigned short* __restrict__ g1t,
                         const unsigned short* __restrict__ g2t,
                         const float* __restrict__ rdeg,
                         float* __restrict__ h, int n,
                         float t0, float t1, float t2, float t3, float t4) {
    if (!LAST && blockIdx.x == 0 && threadIdx.x < 8)   // zero row N of gout
        *(((uint4*)(gout + ((size_t)n << 6))) + threadIdx.x) = make_uint4(0, 0, 0, 0);

    int wid = (blockIdx.x * blockDim.x + threadIdx.x) >> 6;
    int lane = threadIdx.x & 63;
    int half = lane >> 5;
    int r = (lane >> 3) & 3;
    int c = lane & 7;
    int node = wid * 2 + half;
    if (wid * 2 >= n) return;
    bool valid = node < n;
    int beg = valid ? rp[node] : 0;
    int end = valid ? rp[node + 1] : 0;
    int len = end - beg;
    int olen = __shfl_xor(len, 32, 64);
    int mlen = (len > olen) ? len : olen;   // pair max -> uniform trip count

    unsigned acc[4] = {0u, 0u, 0u, 0u};     // packed f16 pairs

    // pipeline state: current rows (in flight), next row indices
    uint4 rc1 = make_uint4(0, 0, 0, 0), rc2 = make_uint4(0, 0, 0, 0);
    int sn1 = n, sn2 = n;
    if (mlen > 0) {
        int j1 = beg + r, j2 = j1 + 4;
        bool o1 = j1 < end, o2 = j2 < end;
        int s1 = csr[o1 ? j1 : 0]; s1 = o1 ? s1 : n;
        int s2 = csr[o2 ? j2 : 0]; s2 = o2 ? s2 : n;
        rc1 = *(const uint4*)(gin + ((size_t)s1 << 6) + (c << 3));
        rc2 = *(const uint4*)(gin + ((size_t)s2 << 6) + (c << 3));
        int j1b = beg + 8 + r, j2b = j1b + 4;
        bool vb = 8 < mlen;
        bool b1 = vb && (j1b < end), b2 = vb && (j2b < end);
        sn1 = csr[b1 ? j1b : 0]; sn1 = b1 ? sn1 : n;
        sn2 = csr[b2 ? j2b : 0]; sn2 = b2 ? sn2 : n;
    }
    for (int i = 0; i < mlen; i += 8) {
        // issue NEXT iteration's rows (independent of rc1/rc2 wait)
        uint4 rn1 = *(const uint4*)(gin + ((size_t)sn1 << 6) + (c << 3));
        uint4 rn2 = *(const uint4*)(gin + ((size_t)sn2 << 6) + (c << 3));
        // prefetch csr two iterations ahead
        int j1n = beg + i + 16 + r, j2n = j1n + 4;
        bool vn = (i + 16) < mlen;
        bool t1c = vn && (j1n < end), t2c = vn && (j2n < end);
        int st1 = csr[t1c ? j1n : 0]; st1 = t1c ? st1 : n;
        int st2 = csr[t2c ? j2n : 0]; st2 = t2c ? st2 : n;
        // accumulate CURRENT rows (packed f16)
        acc[0] = padd2(acc[0], rc1.x); acc[1] = padd2(acc[1], rc1.y);
        acc[2] = padd2(acc[2], rc1.z); acc[3] = padd2(acc[3], rc1.w);
        acc[0] = padd2(acc[0], rc2.x); acc[1] = padd2(acc[1], rc2.y);
        acc[2] = padd2(acc[2], rc2.z); acc[3] = padd2(acc[3], rc2.w);
        // rotate pipeline
        rc1 = rn1; rc2 = rn2;
        sn1 = st1; sn2 = st2;
    }
    #pragma unroll
    for (int m = 8; m <= 16; m <<= 1) {
        #pragma unroll
        for (int i = 0; i < 4; ++i)
            acc[i] = padd2(acc[i], __shfl_xor(acc[i], m, 64));
    }

    if (r == 0 && valid) {                   // lanes 0..7 and 32..39
        size_t off = ((size_t)node << 6) + (c << 3);
        uint4 rr = *(const uint4*)(gin + off);
        float d2 = dinv2[node];
        float v[8];
        v[0] = hlo(rr.x) - d2 * hlo(acc[0]); v[1] = hhi(rr.x) - d2 * hhi(acc[0]);
        v[2] = hlo(rr.y) - d2 * hlo(acc[1]); v[3] = hhi(rr.y) - d2 * hhi(acc[1]);
        v[4] = hlo(rr.z) - d2 * hlo(acc[2]); v[5] = hhi(rr.z) - d2 * hhi(acc[2]);
        v[6] = hlo(rr.w) - d2 * hlo(acc[3]); v[7] = hhi(rr.w) - d2 * hhi(acc[3]);
        if (!LAST) {
            nv4u o;
            o.x = pack2h(v[0], v[1]);
            o.y = pack2h(v[2], v[3]);
            o.z = pack2h(v[4], v[5]);
            o.w = pack2h(v[6], v[7]);
            __builtin_nontemporal_store(o, (nv4u*)(gout + off));
        } else {
            nv4u xv = __builtin_nontemporal_load((const nv4u*)(xb + off));
            nv4u a  = __builtin_nontemporal_load((const nv4u*)(g1t + off));
            nv4u b  = __builtin_nontemporal_load((const nv4u*)(g2t + off));
            float rd = rdeg[node];
            float s1 = rd * t1, s2 = rd * t2, s3 = rd * t3, s4 = rd * t4;
            nv4f h0, h1;
            h0.x = t0 * hlo(xv.x) + s1 * hlo(a.x) + s2 * hlo(b.x) + s3 * hlo(rr.x) + s4 * v[0];
            h0.y = t0 * hhi(xv.x) + s1 * hhi(a.x) + s2 * hhi(b.x) + s3 * hhi(rr.x) + s4 * v[1];
            h0.z = t0 * hlo(xv.y) + s1 * hlo(a.y) + s2 * hlo(b.y) + s3 * hlo(rr.y) + s4 * v[2];
            h0.w = t0 * hhi(xv.y) + s1 * hhi(a.y) + s2 * hhi(b.y) + s3 * hhi(rr.y) + s4 * v[3];
            h1.x = t0 * hlo(xv.z) + s1 * hlo(a.z) + s2 * hlo(b.z) + s3 * hlo(rr.z) + s4 * v[4];
            h1.y = t0 * hhi(xv.z) + s1 * hhi(a.z) + s2 * hhi(b.z) + s3 * hhi(rr.z) + s4 * v[5];
            h1.z = t0 * hlo(xv.w) + s1 * hlo(a.w) + s2 * hlo(b.w) + s3 * hlo(rr.w) + s4 * v[6];
            h1.w = t0 * hhi(xv.w) + s1 * hhi(a.w) + s2 * hhi(b.w) + s3 * hhi(rr.w) + s4 * v[7];
            __builtin_nontemporal_store(h0, (nv4f*)(h + off));
            __builtin_nontemporal_store(h1, (nv4f*)(h + off + 4));
        }
    }
}

extern "C" void kernel_launch(void* const* d_in, const int* in_sizes, int n_in,
                              void* d_out, int out_size, void* d_ws, size_t ws_size,
                              hipStream_t stream) {
    const float* x  = (const float*)d_in[0];
    const int*   ei = (const int*)d_in[1];   // edge_index [2, E] row-major
    const int N = in_sizes[0] / kF;
    const int E = in_sizes[1] / 2;
    const int* src = ei;
    const int* dst = ei + E;
    float* h = (float*)d_out;

    const int K = (N + NB - 1) >> BSHIFT;         // 391 buckets (K <= KMAX)

    // workspace (~72 MB): [btot|deg] (one memset) | rp | cur | dinv2 |
    // rdeg | csr | xb | g0..g3 (g-tables have N+1 rows; row N = zeros)
    char* ws = (char*)d_ws;
    size_t off = 0;
    auto carve = [&](size_t bytes) {
        void* p = ws + off;
        off = (off + bytes + 511) & ~(size_t)511;
        return p;
    };
    size_t gbytes = (size_t)(N + 1) * kF * 2;
    int*            btot    = (int*)carve((size_t)(KMAX + N) * 4);  // btot[KMAX], deg[N]
    int*            deg     = btot + KMAX;
    int*            rp      = (int*)carve((size_t)(N + 1) * 4);
    int*            cur     = (int*)carve((size_t)N * 4);
    float*          dinv2   = (float*)carve((size_t)N * 4);
    float*          rdeg    = (float*)carve((size_t)N * 4);
    int*            csr     = (int*)carve((size_t)E * 4);
    unsigned short* xb      = (unsigned short*)carve((size_t)N * kF * 2);
    unsigned short* g0      = (unsigned short*)carve(gbytes);
    unsigned short* g1      = (unsigned short*)carve(gbytes);
    unsigned short* g2      = (unsigned short*)carve(gbytes);
    unsigned short* g3      = (unsigned short*)carve(gbytes);

    const float theta[5] = {0.6f, -0.4f, 0.3f, -0.2f, 0.1f};
    const int n8 = N * kF / 8;
    const int eblocks = (E + TILE - 1) / TILE;

    // ---- CSR build: hist -> scan -> single scatter ----
    hipMemsetAsync(btot, 0, (size_t)(KMAX + N) * 4, stream);
    k_hist<<<eblocks, 512, 0, stream>>>(dst, deg, btot,
                                        (const float4*)x, (uint4*)xb, n8, E);
    k_scan<<<K, 512, 0, stream>>>(btot, deg, rp, cur, dinv2, rdeg,
                                  (const uint4*)xb, (uint4*)g0, N, E, K);
    k_scatter<<<eblocks, 512, 0, stream>>>(src, dst, cur, csr, E);

    // ---- 4 gather passes; pass 4 fuses the h-combine epilogue ----
    const int nwaves = (N + 1) / 2;                // 2 nodes per wave
    const int gblocks = (nwaves + 3) / 4;          // 4 waves per 256-thread block
    k_gather<false><<<gblocks, 256, 0, stream>>>(rp, csr, g0, dinv2, g1,
                                                 nullptr, nullptr, nullptr, nullptr,
                                                 nullptr, N, 0, 0, 0, 0, 0);
    k_gather<false><<<gblocks, 256, 0, stream>>>(rp, csr, g1, dinv2, g2,
                                                 nullptr, nullptr, nullptr, nullptr,
                                                 nullptr, N, 0, 0, 0, 0, 0);
    k_gather<false><<<gblocks, 256, 0, stream>>>(rp, csr, g2, dinv2, g3,
                                                 nullptr, nullptr, nullptr, nullptr,
                                                 nullptr, N, 0, 0, 0, 0, 0);
    k_gather<true><<<gblocks, 256, 0, stream>>>(rp, csr, g3, dinv2, nullptr,
                                                xb, g1, g2, rdeg, h, N,
                                                theta[0], theta[1], theta[2],
                                                theta[3], theta[4]);
}

// Round 6
// 265.248 us; speedup vs baseline: 1.8741x; 1.6174x over previous
//
#include <hip/hip_runtime.h>
#include <hip/hip_fp16.h>

// PolyConv: h = sum_k theta[k] * L_sym^k x,  L_sym = I - D^{-1/2} A D^{-1/2}
// N=100000 nodes, E=1600000 edges, F=64 features, 5 theta terms.
//
// Round 20: r17 structure restored (244.5us; r19's global-atomic scatter
// was 147us alone from 64B-line write amplification). New: degree-sorted
// node pairing for the gathers. binB also writes deg[node]; a 3-kernel
// LDS-staged counting sort (512 degree bins) builds perm; gather waves
// process nodes in sorted order so the 2 nodes of a wave have near-equal
// degree (trip count = max(len1,len2) -> ~len) and adjacent waves have
// uniform trip counts. csr/rp/dinv2/h remain in original numbering.

constexpr int kF = 64;
constexpr int BSHIFT = 8;             // bucket = dst >> 8  (256 nodes/bucket)
constexpr int NB = 1 << BSHIFT;       // 256 nodes per bucket
constexpr int TILE = 2048;            // edges per phase-A block (4/thread)
constexpr int KMAX = 512;             // array bound for K (=391)
constexpr int DBINS = 512;            // degree-sort bins (deg clamped)

typedef unsigned nv4u __attribute__((ext_vector_type(4)));   // nontemporal-safe
typedef float    nv4f __attribute__((ext_vector_type(4)));

static __device__ __forceinline__ float hlo(unsigned u) {        // low f16 -> f32
    return __half2float(__ushort_as_half((unsigned short)(u & 0xffffu)));
}
static __device__ __forceinline__ float hhi(unsigned u) {        // high f16 -> f32
    return __half2float(__ushort_as_half((unsigned short)(u >> 16)));
}
static __device__ __forceinline__ unsigned pack2h(float a, float b) { // RNE
    return (unsigned)__half_as_ushort(__float2half_rn(a)) |
           ((unsigned)__half_as_ushort(__float2half_rn(b)) << 16);
}
static __device__ __forceinline__ unsigned padd2(unsigned a, unsigned b) {
    __half2 ha = *reinterpret_cast<__half2*>(&a);
    __half2 hb = *reinterpret_cast<__half2*>(&b);
    __half2 hc = __hadd2(ha, hb);                 // v_pk_add_f16
    return *reinterpret_cast<unsigned*>(&hc);
}

// Phase A: multisplit edges into K buckets (hist -> reserve -> direct global
// scatter with LDS cursors). dst/src register-cached across phases.
// Fused x (fp32) -> xb (f16) conversion.
__global__ void k_binA(const int* __restrict__ src, const int* __restrict__ dst,
                       unsigned* __restrict__ pairs, int* __restrict__ gcursor,
                       const float4* __restrict__ x4, uint4* __restrict__ xb4,
                       int n8, int E, int K, int cap) {
    __shared__ int hist[KMAX];
    __shared__ int gb[KMAX];
    const int tid = threadIdx.x;        // blockDim = 512
    const long long tb = (long long)blockIdx.x * TILE;
    const int tcount = (int)min((long long)TILE, (long long)E - tb);

    // fused x -> f16 convert (disjoint slice per block)
    {
        int per = (n8 + gridDim.x - 1) / (int)gridDim.x;
        int b0 = blockIdx.x * per;
        int b1 = min(b0 + per, n8);
        for (int i = b0 + tid; i < b1; i += 512) {
            float4 a = x4[2 * i];
            float4 b = x4[2 * i + 1];
            uint4 o;
            o.x = pack2h(a.x, a.y);
            o.y = pack2h(a.z, a.w);
            o.z = pack2h(b.x, b.y);
            o.w = pack2h(b.z, b.w);
            xb4[i] = o;
        }
    }

    hist[tid] = 0;
    __syncthreads();
    int dc[4], sc[4];
    #pragma unroll
    for (int k = 0; k < 4; ++k) {
        int i = tid + k * 512;
        if (i < tcount) {
            dc[k] = dst[tb + i];
            sc[k] = src[tb + i];
            atomicAdd(&hist[dc[k] >> BSHIFT], 1);
        } else {
            dc[k] = -1;
        }
    }
    __syncthreads();
    int hv = hist[tid];
    gb[tid] = (tid < K && hv > 0) ? atomicAdd(&gcursor[tid], hv) : 0;
    hist[tid] = 0;                       // reuse as local cursor
    __syncthreads();
    #pragma unroll
    for (int k = 0; k < 4; ++k) {
        if (dc[k] >= 0) {
            int d = dc[k];
            int b = d >> BSHIFT;
            int pos = atomicAdd(&hist[b], 1);
            pairs[(size_t)b * cap + gb[b] + pos] =
                ((unsigned)(d & (NB - 1)) << 23) | (unsigned)sc[k];
        }
    }
}

// Phase B: one block (512 thr) per bucket of 256 nodes. In-kernel gbase
// scan, per-node counts -> LDS scan -> rp/dinv2/rdeg/deg, scatter plain
// src ints to csr via absolute LDS cursors, then convert own bucket's
// xb->g0 slice with LDS dinv. Zeroes g0's row N (OOB gather slots).
__global__ void k_binB(const unsigned* __restrict__ pairs, const int* __restrict__ gcursor,
                       int* __restrict__ rp, float* __restrict__ dinv2,
                       float* __restrict__ rdeg, int* __restrict__ degw,
                       int* __restrict__ csr,
                       const uint4* __restrict__ xb, uint4* __restrict__ g0,
                       int N, int E, int K, int cap) {
    __shared__ int gsc[KMAX];
    __shared__ int cnt[NB];
    __shared__ int stmp[NB];
    __shared__ int cur[NB];
    __shared__ float sdinv[NB];
    const int b = blockIdx.x;
    const int tid = threadIdx.x;        // blockDim = 512

    if (b == 0 && tid < 8)               // zero row N of g0
        g0[((size_t)N << 3) + tid] = make_uint4(0, 0, 0, 0);

    int gv = (tid < K) ? gcursor[tid] : 0;
    gsc[tid] = gv;
    __syncthreads();
    for (int o = 1; o < KMAX; o <<= 1) {
        int t = (tid >= o) ? gsc[tid - o] : 0;
        __syncthreads();
        gsc[tid] += t;
        __syncthreads();
    }
    const int ecnt = gcursor[b];
    const int base = gsc[b] - ecnt;     // inclusive - own = exclusive
    const unsigned* bp = pairs + (size_t)b * cap;

    if (tid < NB) cnt[tid] = 0;
    __syncthreads();
    for (int i = tid; i < ecnt; i += 512)
        atomicAdd(&cnt[bp[i] >> 23], 1);
    __syncthreads();
    int v = (tid < NB) ? cnt[tid] : 0;
    if (tid < NB) stmp[tid] = v;
    __syncthreads();
    for (int o = 1; o < NB; o <<= 1) {
        int t = (tid >= o && tid < NB) ? stmp[tid - o] : 0;
        __syncthreads();
        if (tid < NB) stmp[tid] += t;
        __syncthreads();
    }
    int node = (b << BSHIFT) + tid;
    if (tid < NB) {
        int abs0 = base + stmp[tid] - v;            // exclusive, absolute
        cur[tid] = abs0;
        float d = fmaxf((float)v, 1.0f);
        sdinv[tid] = rsqrtf(d);
        if (node < N) {
            rp[node] = abs0;
            dinv2[node] = 1.0f / d;
            rdeg[node]  = sqrtf(d);
            degw[node]  = v;
        }
    }
    if (b == K - 1 && tid == 0) rp[N] = E;
    __syncthreads();
    for (int i = tid; i < ecnt; i += 512) {
        unsigned p = bp[i];
        int pos = atomicAdd(&cur[p >> 23], 1);      // absolute csr index
        csr[pos] = (int)(p & 0x7FFFFFu);
    }
    // fused g0 = f16(dinv * x) for this bucket's nodes (streaming 32KB)
    const int nbase = b << BSHIFT;
    const int qmax = min(NB, N - nbase) << 3;       // 8 uint4 per node
    const uint4* xbp = xb + ((size_t)nbase << 3);
    uint4* g0p = g0 + ((size_t)nbase << 3);
    for (int q = tid; q < qmax; q += 512) {
        float di = sdinv[q >> 3];
        uint4 xv = xbp[q];
        uint4 o;
        o.x = pack2h(di * hlo(xv.x), di * hhi(xv.x));
        o.y = pack2h(di * hlo(xv.y), di * hhi(xv.y));
        o.z = pack2h(di * hlo(xv.z), di * hhi(xv.z));
        o.w = pack2h(di * hlo(xv.w), di * hhi(xv.w));
        g0p[q] = o;
    }
}

// Degree counting-sort (3 tiny kernels over N=100k).
__global__ void k_dhist(const int* __restrict__ deg, int* __restrict__ dbin, int N) {
    __shared__ int h[DBINS];
    int tid = threadIdx.x;
    h[tid] = 0;
    __syncthreads();
    int i = blockIdx.x * DBINS + tid;
    if (i < N) atomicAdd(&h[min(deg[i], DBINS - 1)], 1);
    __syncthreads();
    if (h[tid] > 0) atomicAdd(&dbin[tid], h[tid]);
}

__global__ void k_dscan(const int* __restrict__ dbin, int* __restrict__ dcur) {
    __shared__ int s[DBINS];
    int tid = threadIdx.x;
    int own = dbin[tid];
    s[tid] = own;
    __syncthreads();
    for (int o = 1; o < DBINS; o <<= 1) {
        int t = (tid >= o) ? s[tid - o] : 0;
        __syncthreads();
        s[tid] += t;
        __syncthreads();
    }
    dcur[tid] = s[tid] - own;            // exclusive base
}

__global__ void k_dperm(const int* __restrict__ deg, int* __restrict__ dcur,
                        int* __restrict__ perm, int N) {
    __shared__ int h[DBINS];
    __shared__ int gb[DBINS];
    int tid = threadIdx.x;
    h[tid] = 0;
    __syncthreads();
    int i = blockIdx.x * DBINS + tid;
    int d = (i < N) ? min(deg[i], DBINS - 1) : -1;
    if (d >= 0) atomicAdd(&h[d], 1);
    __syncthreads();
    int hv = h[tid];
    gb[tid] = (hv > 0) ? atomicAdd(&dcur[tid], hv) : 0;
    h[tid] = 0;                          // reuse as local cursor
    __syncthreads();
    if (d >= 0) {
        int pos = atomicAdd(&h[d], 1);
        perm[gb[d] + pos] = i;
    }
}

// TWO nodes per wave in DEGREE-SORTED order (node = perm[idx]): paired
// nodes have near-equal degree -> trip count ~= len, uniform waves.
// f16 feature tables (128B rows), depth-2 software pipeline. Lane l:
// half = l>>5, r = (l>>3)&3, c = l&7. Packed v_pk_add_f16 accumulate;
// OOB slots gather the zero row at index n. Butterfly ^8,^16.
// !LAST epilogue: gout[d] = f16(gin[d] - dinv2[d]*acc)  (+ zero row N)
//  LAST epilogue: h[d] = t0*xb[d] + rdeg[d]*(t1*g1+t2*g2+t3*gin+t4*g4),
//                 g4 = gin[d] - dinv2[d]*acc computed in-register.
template <bool LAST>
__global__ void k_gather(const int* __restrict__ rp, const int* __restrict__ csr,
                         const int* __restrict__ perm,
                         const unsigned short* __restrict__ gin,
                         const float* __restrict__ dinv2,
                         unsigned short* __restrict__ gout,
                         const unsigned short* __restrict__ xb,
                         const unsigned short* __restrict__ g1t,
                         const unsigned short* __restrict__ g2t,
                         const float* __restrict__ rdeg,
                         float* __restrict__ h, int n,
                         float t0, float t1, float t2, float t3, float t4) {
    if (!LAST && blockIdx.x == 0 && threadIdx.x < 8)   // zero row N of gout
        *(((uint4*)(gout + ((size_t)n << 6))) + threadIdx.x) = make_uint4(0, 0, 0, 0);

    int wid = (blockIdx.x * blockDim.x + threadIdx.x) >> 6;
    int lane = threadIdx.x & 63;
    int half = lane >> 5;
    int r = (lane >> 3) & 3;
    int c = lane & 7;
    int idx = wid * 2 + half;
    if (wid * 2 >= n) return;
    bool valid = idx < n;
    int node = valid ? perm[idx] : 0;
    int beg = valid ? rp[node] : 0;
    int end = valid ? rp[node + 1] : 0;
    int len = end - beg;
    int olen = __shfl_xor(len, 32, 64);
    int mlen = (len > olen) ? len : olen;   // pair max -> uniform trip count

    unsigned acc[4] = {0u, 0u, 0u, 0u};     // packed f16 pairs

    // pipeline state: current rows (in flight), next row indices
    uint4 rc1 = make_uint4(0, 0, 0, 0), rc2 = make_uint4(0, 0, 0, 0);
    int sn1 = n, sn2 = n;
    if (mlen > 0) {
        int j1 = beg + r, j2 = j1 + 4;
        bool o1 = j1 < end, o2 = j2 < end;
        int s1 = csr[o1 ? j1 : 0]; s1 = o1 ? s1 : n;
        int s2 = csr[o2 ? j2 : 0]; s2 = o2 ? s2 : n;
        rc1 = *(const uint4*)(gin + ((size_t)s1 << 6) + (c << 3));
        rc2 = *(const uint4*)(gin + ((size_t)s2 << 6) + (c << 3));
        int j1b = beg + 8 + r, j2b = j1b + 4;
        bool vb = 8 < mlen;
        bool b1 = vb && (j1b < end), b2 = vb && (j2b < end);
        sn1 = csr[b1 ? j1b : 0]; sn1 = b1 ? sn1 : n;
        sn2 = csr[b2 ? j2b : 0]; sn2 = b2 ? sn2 : n;
    }
    for (int i = 0; i < mlen; i += 8) {
        // issue NEXT iteration's rows (independent of rc1/rc2 wait)
        uint4 rn1 = *(const uint4*)(gin + ((size_t)sn1 << 6) + (c << 3));
        uint4 rn2 = *(const uint4*)(gin + ((size_t)sn2 << 6) + (c << 3));
        // prefetch csr two iterations ahead
        int j1n = beg + i + 16 + r, j2n = j1n + 4;
        bool vn = (i + 16) < mlen;
        bool t1c = vn && (j1n < end), t2c = vn && (j2n < end);
        int st1 = csr[t1c ? j1n : 0]; st1 = t1c ? st1 : n;
        int st2 = csr[t2c ? j2n : 0]; st2 = t2c ? st2 : n;
        // accumulate CURRENT rows (packed f16)
        acc[0] = padd2(acc[0], rc1.x); acc[1] = padd2(acc[1], rc1.y);
        acc[2] = padd2(acc[2], rc1.z); acc[3] = padd2(acc[3], rc1.w);
        acc[0] = padd2(acc[0], rc2.x); acc[1] = padd2(acc[1], rc2.y);
        acc[2] = padd2(acc[2], rc2.z); acc[3] = padd2(acc[3], rc2.w);
        // rotate pipeline
        rc1 = rn1; rc2 = rn2;
        sn1 = st1; sn2 = st2;
    }
    #pragma unroll
    for (int m = 8; m <= 16; m <<= 1) {
        #pragma unroll
        for (int i = 0; i < 4; ++i)
            acc[i] = padd2(acc[i], __shfl_xor(acc[i], m, 64));
    }

    if (r == 0 && valid) {                   // lanes 0..7 and 32..39
        size_t off = ((size_t)node << 6) + (c << 3);
        uint4 rr = *(const uint4*)(gin + off);
        float d2 = dinv2[node];
        float v[8];
        v[0] = hlo(rr.x) - d2 * hlo(acc[0]); v[1] = hhi(rr.x) - d2 * hhi(acc[0]);
        v[2] = hlo(rr.y) - d2 * hlo(acc[1]); v[3] = hhi(rr.y) - d2 * hhi(acc[1]);
        v[4] = hlo(rr.z) - d2 * hlo(acc[2]); v[5] = hhi(rr.z) - d2 * hhi(acc[2]);
        v[6] = hlo(rr.w) - d2 * hlo(acc[3]); v[7] = hhi(rr.w) - d2 * hhi(acc[3]);
        if (!LAST) {
            nv4u o;
            o.x = pack2h(v[0], v[1]);
            o.y = pack2h(v[2], v[3]);
            o.z = pack2h(v[4], v[5]);
            o.w = pack2h(v[6], v[7]);
            __builtin_nontemporal_store(o, (nv4u*)(gout + off));
        } else {
            nv4u xv = __builtin_nontemporal_load((const nv4u*)(xb + off));
            nv4u a  = __builtin_nontemporal_load((const nv4u*)(g1t + off));
            nv4u b  = __builtin_nontemporal_load((const nv4u*)(g2t + off));
            float rd = rdeg[node];
            float s1 = rd * t1, s2 = rd * t2, s3 = rd * t3, s4 = rd * t4;
            nv4f h0, h1;
            h0.x = t0 * hlo(xv.x) + s1 * hlo(a.x) + s2 * hlo(b.x) + s3 * hlo(rr.x) + s4 * v[0];
            h0.y = t0 * hhi(xv.x) + s1 * hhi(a.x) + s2 * hhi(b.x) + s3 * hhi(rr.x) + s4 * v[1];
            h0.z = t0 * hlo(xv.y) + s1 * hlo(a.y) + s2 * hlo(b.y) + s3 * hlo(rr.y) + s4 * v[2];
            h0.w = t0 * hhi(xv.y) + s1 * hhi(a.y) + s2 * hhi(b.y) + s3 * hhi(rr.y) + s4 * v[3];
            h1.x = t0 * hlo(xv.z) + s1 * hlo(a.z) + s2 * hlo(b.z) + s3 * hlo(rr.z) + s4 * v[4];
            h1.y = t0 * hhi(xv.z) + s1 * hhi(a.z) + s2 * hhi(b.z) + s3 * hhi(rr.z) + s4 * v[5];
            h1.z = t0 * hlo(xv.w) + s1 * hlo(a.w) + s2 * hlo(b.w) + s3 * hlo(rr.w) + s4 * v[6];
            h1.w = t0 * hhi(xv.w) + s1 * hhi(a.w) + s2 * hhi(b.w) + s3 * hhi(rr.w) + s4 * v[7];
            __builtin_nontemporal_store(h0, (nv4f*)(h + off));
            __builtin_nontemporal_store(h1, (nv4f*)(h + off + 4));
        }
    }
}

extern "C" void kernel_launch(void* const* d_in, const int* in_sizes, int n_in,
                              void* d_out, int out_size, void* d_ws, size_t ws_size,
                              hipStream_t stream) {
    const float* x  = (const float*)d_in[0];
    const int*   ei = (const int*)d_in[1];   // edge_index [2, E] row-major
    const int N = in_sizes[0] / kF;
    const int E = in_sizes[1] / 2;
    const int* src = ei;
    const int* dst = ei + E;
    float* h = (float*)d_out;

    const int K = (N + NB - 1) >> BSHIFT;         // 391 buckets (K <= KMAX)
    const int cap = 2 * ((E + K - 1) / K);        // per-bucket capacity

    // workspace (~73 MB): gcursor+dbin (one memset) | dcur | deg | perm |
    // rp | dinv2 | rdeg | csr | xb | g0 | g1 (aliases pairs) | g2 | g3
    char* ws = (char*)d_ws;
    size_t off = 0;
    auto carve = [&](size_t bytes) {
        void* p = ws + off;
        off = (off + bytes + 511) & ~(size_t)511;
        return p;
    };
    size_t gbytes = (size_t)(N + 1) * kF * 2;
    int*            gcursor = (int*)carve((size_t)KMAX * 4);   // 2048B, 512-aligned
    int*            dbin    = (int*)carve((size_t)DBINS * 4);  // contiguous after
    int*            dcur    = (int*)carve((size_t)DBINS * 4);
    int*            deg     = (int*)carve((size_t)N * 4);
    int*            perm    = (int*)carve((size_t)N * 4);
    int*            rp      = (int*)carve((size_t)(N + 1) * 4);
    float*          dinv2   = (float*)carve((size_t)N * 4);
    float*          rdeg    = (float*)carve((size_t)N * 4);
    int*            csr     = (int*)carve((size_t)E * 4);
    unsigned short* xb      = (unsigned short*)carve((size_t)N * kF * 2);
    unsigned short* g0      = (unsigned short*)carve(gbytes);
    size_t pbytes = (size_t)K * cap * 4;
    unsigned short* g1      = (unsigned short*)carve(gbytes > pbytes ? gbytes : pbytes);
    unsigned short* g2      = (unsigned short*)carve(gbytes);
    unsigned short* g3      = (unsigned short*)carve(gbytes);
    unsigned*       pairs   = (unsigned*)g1;       // alias (dead after binB)

    const float theta[5] = {0.6f, -0.4f, 0.3f, -0.2f, 0.1f};
    const int n8 = N * kF / 8;
    const int dblocks = (N + DBINS - 1) / DBINS;

    // ---- CSR build (multisplit) with fused x->f16 convert and g0 ----
    hipMemsetAsync(gcursor, 0, (size_t)(KMAX + DBINS) * 4, stream);
    k_binA<<<(E + TILE - 1) / TILE, 512, 0, stream>>>(src, dst, pairs, gcursor,
                                                      (const float4*)x, (uint4*)xb,
                                                      n8, E, K, cap);
    k_binB<<<K, 512, 0, stream>>>(pairs, gcursor, rp, dinv2, rdeg, deg, csr,
                                  (const uint4*)xb, (uint4*)g0, N, E, K, cap);

    // ---- degree counting-sort -> perm ----
    k_dhist<<<dblocks, DBINS, 0, stream>>>(deg, dbin, N);
    k_dscan<<<1, DBINS, 0, stream>>>(dbin, dcur);
    k_dperm<<<dblocks, DBINS, 0, stream>>>(deg, dcur, perm, N);

    // ---- 4 gather passes (degree-sorted); pass 4 fuses h-combine ----
    const int nwaves = (N + 1) / 2;                // 2 nodes per wave
    const int gblocks = (nwaves + 3) / 4;          // 4 waves per 256-thread block
    k_gather<false><<<gblocks, 256, 0, stream>>>(rp, csr, perm, g0, dinv2, g1,
                                                 nullptr, nullptr, nullptr, nullptr,
                                                 nullptr, N, 0, 0, 0, 0, 0);
    k_gather<false><<<gblocks, 256, 0, stream>>>(rp, csr, perm, g1, dinv2, g2,
                                                 nullptr, nullptr, nullptr, nullptr,
                                                 nullptr, N, 0, 0, 0, 0, 0);
    k_gather<false><<<gblocks, 256, 0, stream>>>(rp, csr, perm, g2, dinv2, g3,
                                                 nullptr, nullptr, nullptr, nullptr,
                                                 nullptr, N, 0, 0, 0, 0, 0);
    k_gather<true><<<gblocks, 256, 0, stream>>>(rp, csr, perm, g3, dinv2, nullptr,
                                                xb, g1, g2, rdeg, h, N,
                                                theta[0], theta[1], theta[2],
                                                theta[3], theta[4]);
}

// Round 7
// 243.176 us; speedup vs baseline: 2.0442x; 1.0908x over previous
//
#include <hip/hip_runtime.h>
#include <hip/hip_fp16.h>

// PolyConv: h = sum_k theta[k] * L_sym^k x,  L_sym = I - D^{-1/2} A D^{-1/2}
// N=100000 nodes, E=1600000 edges, F=64 features, 5 theta terms.
//
// Round 21: r17 structure (degree sort of r20 reverted: -21us locality
// loss). New: per-wave critical-path shortening in the gathers.
//  - csr0[N][8]: first 8 csr slots per node (padded with N = zero row),
//    written by binB after its csr scatter (L2-hot readback). Gather
//    prologue reads row indices from csr0 -- independent of rp[node] --
//    collapsing the serial chain rp -> csr -> row to (csr0 || rp) -> row.
//  - epilogue loads (own row rr, dinv2, LAST: xb/g1/g2/rdeg) hoisted to
//    the prologue under the r==0 exec mask: issued ~2 loop-trips early.

constexpr int kF = 64;
constexpr int BSHIFT = 8;             // bucket = dst >> 8  (256 nodes/bucket)
constexpr int NB = 1 << BSHIFT;       // 256 nodes per bucket
constexpr int TILE = 2048;            // edges per phase-A block (4/thread)
constexpr int KMAX = 512;             // array bound for K (=391)

typedef unsigned nv4u __attribute__((ext_vector_type(4)));   // nontemporal-safe
typedef float    nv4f __attribute__((ext_vector_type(4)));

static __device__ __forceinline__ float hlo(unsigned u) {        // low f16 -> f32
    return __half2float(__ushort_as_half((unsigned short)(u & 0xffffu)));
}
static __device__ __forceinline__ float hhi(unsigned u) {        // high f16 -> f32
    return __half2float(__ushort_as_half((unsigned short)(u >> 16)));
}
static __device__ __forceinline__ unsigned pack2h(float a, float b) { // RNE
    return (unsigned)__half_as_ushort(__float2half_rn(a)) |
           ((unsigned)__half_as_ushort(__float2half_rn(b)) << 16);
}
static __device__ __forceinline__ unsigned padd2(unsigned a, unsigned b) {
    __half2 ha = *reinterpret_cast<__half2*>(&a);
    __half2 hb = *reinterpret_cast<__half2*>(&b);
    __half2 hc = __hadd2(ha, hb);                 // v_pk_add_f16
    return *reinterpret_cast<unsigned*>(&hc);
}

// Phase A: multisplit edges into K buckets (hist -> reserve -> direct global
// scatter with LDS cursors). dst/src register-cached across phases.
// Fused x (fp32) -> xb (f16) conversion.
__global__ void k_binA(const int* __restrict__ src, const int* __restrict__ dst,
                       unsigned* __restrict__ pairs, int* __restrict__ gcursor,
                       const float4* __restrict__ x4, uint4* __restrict__ xb4,
                       int n8, int E, int K, int cap) {
    __shared__ int hist[KMAX];
    __shared__ int gb[KMAX];
    const int tid = threadIdx.x;        // blockDim = 512
    const long long tb = (long long)blockIdx.x * TILE;
    const int tcount = (int)min((long long)TILE, (long long)E - tb);

    // fused x -> f16 convert (disjoint slice per block)
    {
        int per = (n8 + gridDim.x - 1) / (int)gridDim.x;
        int b0 = blockIdx.x * per;
        int b1 = min(b0 + per, n8);
        for (int i = b0 + tid; i < b1; i += 512) {
            float4 a = x4[2 * i];
            float4 b = x4[2 * i + 1];
            uint4 o;
            o.x = pack2h(a.x, a.y);
            o.y = pack2h(a.z, a.w);
            o.z = pack2h(b.x, b.y);
            o.w = pack2h(b.z, b.w);
            xb4[i] = o;
        }
    }

    hist[tid] = 0;
    __syncthreads();
    int dc[4], sc[4];
    #pragma unroll
    for (int k = 0; k < 4; ++k) {
        int i = tid + k * 512;
        if (i < tcount) {
            dc[k] = dst[tb + i];
            sc[k] = src[tb + i];
            atomicAdd(&hist[dc[k] >> BSHIFT], 1);
        } else {
            dc[k] = -1;
        }
    }
    __syncthreads();
    int hv = hist[tid];
    gb[tid] = (tid < K && hv > 0) ? atomicAdd(&gcursor[tid], hv) : 0;
    hist[tid] = 0;                       // reuse as local cursor
    __syncthreads();
    #pragma unroll
    for (int k = 0; k < 4; ++k) {
        if (dc[k] >= 0) {
            int d = dc[k];
            int b = d >> BSHIFT;
            int pos = atomicAdd(&hist[b], 1);
            pairs[(size_t)b * cap + gb[b] + pos] =
                ((unsigned)(d & (NB - 1)) << 23) | (unsigned)sc[k];
        }
    }
}

// Phase B: one block (512 thr) per bucket of 256 nodes. In-kernel gbase
// scan, per-node counts -> LDS scan -> rp/dinv2/rdeg, scatter plain src
// ints to csr via absolute LDS cursors, write csr0 (first 8 slots per
// node, padded with N), then convert own bucket's xb->g0 slice with LDS
// dinv. Zeroes g0's row N (OOB gather slots).
__global__ void k_binB(const unsigned* __restrict__ pairs, const int* __restrict__ gcursor,
                       int* __restrict__ rp, float* __restrict__ dinv2,
                       float* __restrict__ rdeg, int* __restrict__ csr,
                       int* __restrict__ csr0,
                       const uint4* __restrict__ xb, uint4* __restrict__ g0,
                       int N, int E, int K, int cap) {
    __shared__ int gsc[KMAX];
    __shared__ int cnt[NB];
    __shared__ int stmp[NB];
    __shared__ int cur[NB];
    __shared__ float sdinv[NB];
    const int b = blockIdx.x;
    const int tid = threadIdx.x;        // blockDim = 512

    if (b == 0 && tid < 8)               // zero row N of g0
        g0[((size_t)N << 3) + tid] = make_uint4(0, 0, 0, 0);

    int gv = (tid < K) ? gcursor[tid] : 0;
    gsc[tid] = gv;
    __syncthreads();
    for (int o = 1; o < KMAX; o <<= 1) {
        int t = (tid >= o) ? gsc[tid - o] : 0;
        __syncthreads();
        gsc[tid] += t;
        __syncthreads();
    }
    const int ecnt = gcursor[b];
    const int base = gsc[b] - ecnt;     // inclusive - own = exclusive
    const unsigned* bp = pairs + (size_t)b * cap;

    if (tid < NB) cnt[tid] = 0;
    __syncthreads();
    for (int i = tid; i < ecnt; i += 512)
        atomicAdd(&cnt[bp[i] >> 23], 1);
    __syncthreads();
    int v = (tid < NB) ? cnt[tid] : 0;
    if (tid < NB) stmp[tid] = v;
    __syncthreads();
    for (int o = 1; o < NB; o <<= 1) {
        int t = (tid >= o && tid < NB) ? stmp[tid - o] : 0;
        __syncthreads();
        if (tid < NB) stmp[tid] += t;
        __syncthreads();
    }
    int node = (b << BSHIFT) + tid;
    if (tid < NB) {
        int abs0 = base + stmp[tid] - v;            // exclusive, absolute
        cur[tid] = abs0;
        float d = fmaxf((float)v, 1.0f);
        sdinv[tid] = rsqrtf(d);
        if (node < N) {
            rp[node] = abs0;
            dinv2[node] = 1.0f / d;
            rdeg[node]  = sqrtf(d);
        }
    }
    if (b == K - 1 && tid == 0) rp[N] = E;
    __syncthreads();
    for (int i = tid; i < ecnt; i += 512) {
        unsigned p = bp[i];
        int pos = atomicAdd(&cur[p >> 23], 1);      // absolute csr index
        csr[pos] = (int)(p & 0x7FFFFFu);
    }
    __syncthreads();                                 // csr of this bucket done
    // csr0: first 8 slots per node, padded with N (zero row)
    if (tid < NB && node < N) {
        int abs0 = base + stmp[tid] - v;
        int4 q0, q1;
        q0.x = (0 < v) ? csr[abs0 + 0] : N;
        q0.y = (1 < v) ? csr[abs0 + 1] : N;
        q0.z = (2 < v) ? csr[abs0 + 2] : N;
        q0.w = (3 < v) ? csr[abs0 + 3] : N;
        q1.x = (4 < v) ? csr[abs0 + 4] : N;
        q1.y = (5 < v) ? csr[abs0 + 5] : N;
        q1.z = (6 < v) ? csr[abs0 + 6] : N;
        q1.w = (7 < v) ? csr[abs0 + 7] : N;
        *(int4*)(csr0 + ((size_t)node << 3))     = q0;
        *(int4*)(csr0 + ((size_t)node << 3) + 4) = q1;
    }
    // fused g0 = f16(dinv * x) for this bucket's nodes (streaming 32KB)
    const int nbase = b << BSHIFT;
    const int qmax = min(NB, N - nbase) << 3;       // 8 uint4 per node
    const uint4* xbp = xb + ((size_t)nbase << 3);
    uint4* g0p = g0 + ((size_t)nbase << 3);
    for (int q = tid; q < qmax; q += 512) {
        float di = sdinv[q >> 3];
        uint4 xv = xbp[q];
        uint4 o;
        o.x = pack2h(di * hlo(xv.x), di * hhi(xv.x));
        o.y = pack2h(di * hlo(xv.y), di * hhi(xv.y));
        o.z = pack2h(di * hlo(xv.z), di * hhi(xv.z));
        o.w = pack2h(di * hlo(xv.w), di * hhi(xv.w));
        g0p[q] = o;
    }
}

// TWO nodes per wave, f16 feature tables (128B rows), depth-2 software
// pipeline. Lane l: half = l>>5, r = (l>>3)&3, c = l&7.
// First-iteration row indices come from csr0 (no rp dependency); epilogue
// node-addressed loads are hoisted to the prologue under the r==0 mask.
// Packed v_pk_add_f16 accumulate; OOB slots gather zero row n.
// !LAST epilogue: gout[d] = f16(gin[d] - dinv2[d]*acc)  (+ zero row N)
//  LAST epilogue: h[d] = t0*xb[d] + rdeg[d]*(t1*g1+t2*g2+t3*gin+t4*g4),
//                 g4 = gin[d] - dinv2[d]*acc computed in-register.
template <bool LAST>
__global__ void k_gather(const int* __restrict__ rp, const int* __restrict__ csr,
                         const int* __restrict__ csr0,
                         const unsigned short* __restrict__ gin,
                         const float* __restrict__ dinv2,
                         unsigned short* __restrict__ gout,
                         const unsigned short* __restrict__ xb,
                         const unsigned short* __restrict__ g1t,
                         const unsigned short* __restrict__ g2t,
                         const float* __restrict__ rdeg,
                         float* __restrict__ h, int n,
                         float t0, float t1, float t2, float t3, float t4) {
    if (!LAST && blockIdx.x == 0 && threadIdx.x < 8)   // zero row N of gout
        *(((uint4*)(gout + ((size_t)n << 6))) + threadIdx.x) = make_uint4(0, 0, 0, 0);

    int wid = (blockIdx.x * blockDim.x + threadIdx.x) >> 6;
    int lane = threadIdx.x & 63;
    int half = lane >> 5;
    int r = (lane >> 3) & 3;
    int c = lane & 7;
    int node = wid * 2 + half;
    if (wid * 2 >= n) return;
    bool valid = node < n;

    // first-iteration row indices: independent of rp (breaks the chain)
    int s1 = n, s2 = n;
    if (valid) {
        s1 = csr0[((size_t)node << 3) + r];
        s2 = csr0[((size_t)node << 3) + r + 4];
    }
    int beg = valid ? rp[node] : 0;
    int end = valid ? rp[node + 1] : 0;

    // hoisted epilogue loads (node-addressed, exec-masked to 16 lanes)
    const bool ep = (r == 0) && valid;
    size_t off = ((size_t)node << 6) + (c << 3);
    uint4 rr = make_uint4(0, 0, 0, 0);
    float d2 = 0.f, rd = 0.f;
    nv4u xv = {0u, 0u, 0u, 0u}, aa = {0u, 0u, 0u, 0u}, bb = {0u, 0u, 0u, 0u};
    if (ep) {
        rr = *(const uint4*)(gin + off);
        d2 = dinv2[node];
        if (LAST) {
            xv = __builtin_nontemporal_load((const nv4u*)(xb + off));
            aa = __builtin_nontemporal_load((const nv4u*)(g1t + off));
            bb = __builtin_nontemporal_load((const nv4u*)(g2t + off));
            rd = rdeg[node];
        }
    }

    int len = end - beg;
    int olen = __shfl_xor(len, 32, 64);
    int mlen = (len > olen) ? len : olen;   // pair max -> uniform trip count

    unsigned acc[4] = {0u, 0u, 0u, 0u};     // packed f16 pairs

    // pipeline state: current rows (in flight), next row indices
    uint4 rc1 = *(const uint4*)(gin + ((size_t)s1 << 6) + (c << 3));
    uint4 rc2 = *(const uint4*)(gin + ((size_t)s2 << 6) + (c << 3));
    int sn1 = n, sn2 = n;
    {
        int j1b = beg + 8 + r, j2b = j1b + 4;
        bool vb = 8 < mlen;
        bool b1 = vb && (j1b < end), b2 = vb && (j2b < end);
        sn1 = csr[b1 ? j1b : 0]; sn1 = b1 ? sn1 : n;
        sn2 = csr[b2 ? j2b : 0]; sn2 = b2 ? sn2 : n;
    }
    for (int i = 0; i < mlen; i += 8) {
        // issue NEXT iteration's rows (independent of rc1/rc2 wait)
        uint4 rn1 = *(const uint4*)(gin + ((size_t)sn1 << 6) + (c << 3));
        uint4 rn2 = *(const uint4*)(gin + ((size_t)sn2 << 6) + (c << 3));
        // prefetch csr two iterations ahead
        int j1n = beg + i + 16 + r, j2n = j1n + 4;
        bool vn = (i + 16) < mlen;
        bool t1c = vn && (j1n < end), t2c = vn && (j2n < end);
        int st1 = csr[t1c ? j1n : 0]; st1 = t1c ? st1 : n;
        int st2 = csr[t2c ? j2n : 0]; st2 = t2c ? st2 : n;
        // accumulate CURRENT rows (packed f16)
        acc[0] = padd2(acc[0], rc1.x); acc[1] = padd2(acc[1], rc1.y);
        acc[2] = padd2(acc[2], rc1.z); acc[3] = padd2(acc[3], rc1.w);
        acc[0] = padd2(acc[0], rc2.x); acc[1] = padd2(acc[1], rc2.y);
        acc[2] = padd2(acc[2], rc2.z); acc[3] = padd2(acc[3], rc2.w);
        // rotate pipeline
        rc1 = rn1; rc2 = rn2;
        sn1 = st1; sn2 = st2;
    }
    #pragma unroll
    for (int m = 8; m <= 16; m <<= 1) {
        #pragma unroll
        for (int i = 0; i < 4; ++i)
            acc[i] = padd2(acc[i], __shfl_xor(acc[i], m, 64));
    }

    if (ep) {                                // lanes 0..7 and 32..39
        float v[8];
        v[0] = hlo(rr.x) - d2 * hlo(acc[0]); v[1] = hhi(rr.x) - d2 * hhi(acc[0]);
        v[2] = hlo(rr.y) - d2 * hlo(acc[1]); v[3] = hhi(rr.y) - d2 * hhi(acc[1]);
        v[4] = hlo(rr.z) - d2 * hlo(acc[2]); v[5] = hhi(rr.z) - d2 * hhi(acc[2]);
        v[6] = hlo(rr.w) - d2 * hlo(acc[3]); v[7] = hhi(rr.w) - d2 * hhi(acc[3]);
        if (!LAST) {
            nv4u o;
            o.x = pack2h(v[0], v[1]);
            o.y = pack2h(v[2], v[3]);
            o.z = pack2h(v[4], v[5]);
            o.w = pack2h(v[6], v[7]);
            __builtin_nontemporal_store(o, (nv4u*)(gout + off));
        } else {
            float s1f = rd * t1, s2f = rd * t2, s3f = rd * t3, s4f = rd * t4;
            nv4f h0, h1;
            h0.x = t0 * hlo(xv.x) + s1f * hlo(aa.x) + s2f * hlo(bb.x) + s3f * hlo(rr.x) + s4f * v[0];
            h0.y = t0 * hhi(xv.x) + s1f * hhi(aa.x) + s2f * hhi(bb.x) + s3f * hhi(rr.x) + s4f * v[1];
            h0.z = t0 * hlo(xv.y) + s1f * hlo(aa.y) + s2f * hlo(bb.y) + s3f * hlo(rr.y) + s4f * v[2];
            h0.w = t0 * hhi(xv.y) + s1f * hhi(aa.y) + s2f * hhi(bb.y) + s3f * hhi(rr.y) + s4f * v[3];
            h1.x = t0 * hlo(xv.z) + s1f * hlo(aa.z) + s2f * hlo(bb.z) + s3f * hlo(rr.z) + s4f * v[4];
            h1.y = t0 * hhi(xv.z) + s1f * hhi(aa.z) + s2f * hhi(bb.z) + s3f * hhi(rr.z) + s4f * v[5];
            h1.z = t0 * hlo(xv.w) + s1f * hlo(aa.w) + s2f * hlo(bb.w) + s3f * hlo(rr.w) + s4f * v[6];
            h1.w = t0 * hhi(xv.w) + s1f * hhi(aa.w) + s2f * hhi(bb.w) + s3f * hhi(rr.w) + s4f * v[7];
            __builtin_nontemporal_store(h0, (nv4f*)(h + off));
            __builtin_nontemporal_store(h1, (nv4f*)(h + off + 4));
        }
    }
}

extern "C" void kernel_launch(void* const* d_in, const int* in_sizes, int n_in,
                              void* d_out, int out_size, void* d_ws, size_t ws_size,
                              hipStream_t stream) {
    const float* x  = (const float*)d_in[0];
    const int*   ei = (const int*)d_in[1];   // edge_index [2, E] row-major
    const int N = in_sizes[0] / kF;
    const int E = in_sizes[1] / 2;
    const int* src = ei;
    const int* dst = ei + E;
    float* h = (float*)d_out;

    const int K = (N + NB - 1) >> BSHIFT;         // 391 buckets (K <= KMAX)
    const int cap = 2 * ((E + K - 1) / K);        // per-bucket capacity

    // workspace (~76 MB): gcursor | rp | dinv2 | rdeg | csr | csr0 | xb |
    // g0 | g1 (aliases pairs; pairs dead after binB) | g2 | g3
    char* ws = (char*)d_ws;
    size_t off = 0;
    auto carve = [&](size_t bytes) {
        void* p = ws + off;
        off = (off + bytes + 511) & ~(size_t)511;
        return p;
    };
    size_t gbytes = (size_t)(N + 1) * kF * 2;
    int*            gcursor = (int*)carve((size_t)KMAX * 4);
    int*            rp      = (int*)carve((size_t)(N + 1) * 4);
    float*          dinv2   = (float*)carve((size_t)N * 4);
    float*          rdeg    = (float*)carve((size_t)N * 4);
    int*            csr     = (int*)carve((size_t)E * 4);
    int*            csr0    = (int*)carve((size_t)N * 8 * 4);
    unsigned short* xb      = (unsigned short*)carve((size_t)N * kF * 2);
    unsigned short* g0      = (unsigned short*)carve(gbytes);
    size_t pbytes = (size_t)K * cap * 4;
    unsigned short* g1      = (unsigned short*)carve(gbytes > pbytes ? gbytes : pbytes);
    unsigned short* g2      = (unsigned short*)carve(gbytes);
    unsigned short* g3      = (unsigned short*)carve(gbytes);
    unsigned*       pairs   = (unsigned*)g1;       // alias (dead after binB)

    const float theta[5] = {0.6f, -0.4f, 0.3f, -0.2f, 0.1f};
    const int n8 = N * kF / 8;

    // ---- CSR build (multisplit) with fused x->f16 convert and g0 ----
    hipMemsetAsync(gcursor, 0, (size_t)KMAX * 4, stream);
    k_binA<<<(E + TILE - 1) / TILE, 512, 0, stream>>>(src, dst, pairs, gcursor,
                                                      (const float4*)x, (uint4*)xb,
                                                      n8, E, K, cap);
    k_binB<<<K, 512, 0, stream>>>(pairs, gcursor, rp, dinv2, rdeg, csr, csr0,
                                  (const uint4*)xb, (uint4*)g0, N, E, K, cap);

    // ---- 4 gather passes; pass 4 fuses the h-combine epilogue ----
    const int nwaves = (N + 1) / 2;                // 2 nodes per wave
    const int gblocks = (nwaves + 3) / 4;          // 4 waves per 256-thread block
    k_gather<false><<<gblocks, 256, 0, stream>>>(rp, csr, csr0, g0, dinv2, g1,
                                                 nullptr, nullptr, nullptr, nullptr,
                                                 nullptr, N, 0, 0, 0, 0, 0);
    k_gather<false><<<gblocks, 256, 0, stream>>>(rp, csr, csr0, g1, dinv2, g2,
                                                 nullptr, nullptr, nullptr, nullptr,
                                                 nullptr, N, 0, 0, 0, 0, 0);
    k_gather<false><<<gblocks, 256, 0, stream>>>(rp, csr, csr0, g2, dinv2, g3,
                                                 nullptr, nullptr, nullptr, nullptr,
                                                 nullptr, N, 0, 0, 0, 0, 0);
    k_gather<true><<<gblocks, 256, 0, stream>>>(rp, csr, csr0, g3, dinv2, nullptr,
                                                xb, g1, g2, rdeg, h, N,
                                                theta[0], theta[1], theta[2],
                                                theta[3], theta[4]);
}

// Round 8
// 237.748 us; speedup vs baseline: 2.0909x; 1.0228x over previous
//
#include <hip/hip_runtime.h>
#include <hip/hip_fp16.h>

// PolyConv: h = sum_k theta[k] * L_sym^k x,  L_sym = I - D^{-1/2} A D^{-1/2}
// N=100000 nodes, E=1600000 edges, F=64 features, 5 theta terms.
//
// Round 22: r21 + LDS-staged bucket-sorted binA. Old binA scattered 4B
// pairs entries directly to global bucket regions from 782 blocks (~5
// edges/bucket/block): every 64B line of pairs written by ~3 blocks on
// different XCDs -> line ping-pong, ~16x write amplification (r5 measured
// the same pathology at 109MB writes for 6.4MB data). New binA: 8192-edge
// tiles (16/thread), block-local counting sort into LDS (stage 32KB +
// bucket ids 16KB), then sequential bucket-ordered write-out: ~84B
// coalesced runs, one line transfer per run. binB order-agnostic.

constexpr int kF = 64;
constexpr int BSHIFT = 8;             // bucket = dst >> 8  (256 nodes/bucket)
constexpr int NB = 1 << BSHIFT;       // 256 nodes per bucket
constexpr int TILEA = 8192;           // edges per binA block (16/thread)
constexpr int KMAX = 512;             // array bound for K (=391)

typedef unsigned nv4u __attribute__((ext_vector_type(4)));   // nontemporal-safe
typedef float    nv4f __attribute__((ext_vector_type(4)));

static __device__ __forceinline__ float hlo(unsigned u) {        // low f16 -> f32
    return __half2float(__ushort_as_half((unsigned short)(u & 0xffffu)));
}
static __device__ __forceinline__ float hhi(unsigned u) {        // high f16 -> f32
    return __half2float(__ushort_as_half((unsigned short)(u >> 16)));
}
static __device__ __forceinline__ unsigned pack2h(float a, float b) { // RNE
    return (unsigned)__half_as_ushort(__float2half_rn(a)) |
           ((unsigned)__half_as_ushort(__float2half_rn(b)) << 16);
}
static __device__ __forceinline__ unsigned padd2(unsigned a, unsigned b) {
    __half2 ha = *reinterpret_cast<__half2*>(&a);
    __half2 hb = *reinterpret_cast<__half2*>(&b);
    __half2 hc = __hadd2(ha, hb);                 // v_pk_add_f16
    return *reinterpret_cast<unsigned*>(&hc);
}

// Phase A: multisplit edges into K buckets. Per 8192-edge tile: LDS
// histogram -> KMAX scan -> LDS counting-sort (stage) -> global reserve
// -> bucket-ordered coalesced write-out. Fused x (fp32) -> xb (f16).
__global__ void k_binA(const int* __restrict__ src, const int* __restrict__ dst,
                       unsigned* __restrict__ pairs, int* __restrict__ gcursor,
                       const float4* __restrict__ x4, uint4* __restrict__ xb4,
                       int n8, int E, int K, int cap) {
    __shared__ unsigned stage[TILEA];        // 32 KB bucket-sorted entries
    __shared__ unsigned short stageB[TILEA]; // 16 KB bucket id per slot
    __shared__ int hist[KMAX];               // counts -> cursors
    __shared__ int lb[KMAX];                 // local exclusive base
    __shared__ int gb[KMAX];                 // global base per bucket
    const int tid = threadIdx.x;        // blockDim = 512
    const long long tb = (long long)blockIdx.x * TILEA;
    const int tcount = (int)min((long long)TILEA, (long long)E - tb);

    // fused x -> f16 convert (disjoint slice per block)
    {
        int per = (n8 + gridDim.x - 1) / (int)gridDim.x;
        int b0 = blockIdx.x * per;
        int b1 = min(b0 + per, n8);
        for (int i = b0 + tid; i < b1; i += 512) {
            float4 a = x4[2 * i];
            float4 b = x4[2 * i + 1];
            uint4 o;
            o.x = pack2h(a.x, a.y);
            o.y = pack2h(a.z, a.w);
            o.z = pack2h(b.x, b.y);
            o.w = pack2h(b.z, b.w);
            xb4[i] = o;
        }
    }

    hist[tid] = 0;
    __syncthreads();
    int dc[16], sc[16];
    #pragma unroll
    for (int k = 0; k < 16; ++k) {
        int i = tid + k * 512;
        if (i < tcount) {
            dc[k] = dst[tb + i];
            sc[k] = src[tb + i];
            atomicAdd(&hist[dc[k] >> BSHIFT], 1);
        } else {
            dc[k] = -1;
        }
    }
    __syncthreads();
    const int cnt = hist[tid];
    lb[tid] = cnt;
    __syncthreads();
    for (int o = 1; o < KMAX; o <<= 1) {
        int t = (tid >= o) ? lb[tid - o] : 0;
        __syncthreads();
        lb[tid] += t;
        __syncthreads();
    }
    const int excl = lb[tid] - cnt;          // local exclusive base
    __syncthreads();
    lb[tid] = excl;
    gb[tid] = (tid < K && cnt > 0) ? atomicAdd(&gcursor[tid], cnt) : 0;
    hist[tid] = excl;                        // reuse as LDS scatter cursor
    __syncthreads();
    #pragma unroll
    for (int k = 0; k < 16; ++k) {
        if (dc[k] >= 0) {
            int d = dc[k];
            int b = d >> BSHIFT;
            int pos = atomicAdd(&hist[b], 1);
            stage[pos]  = ((unsigned)(d & (NB - 1)) << 23) | (unsigned)sc[k];
            stageB[pos] = (unsigned short)b;
        }
    }
    __syncthreads();
    // bucket-ordered write-out: consecutive j -> consecutive addresses
    for (int j = tid; j < tcount; j += 512) {
        int b = stageB[j];
        pairs[(size_t)b * cap + gb[b] + (j - lb[b])] = stage[j];
    }
}

// Phase B: one block (512 thr) per bucket of 256 nodes. In-kernel gbase
// scan, per-node counts -> LDS scan -> rp/dinv2/rdeg, scatter plain src
// ints to csr via absolute LDS cursors, write csr0 (first 8 slots per
// node, padded with N), then convert own bucket's xb->g0 slice with LDS
// dinv. Zeroes g0's row N (OOB gather slots).
__global__ void k_binB(const unsigned* __restrict__ pairs, const int* __restrict__ gcursor,
                       int* __restrict__ rp, float* __restrict__ dinv2,
                       float* __restrict__ rdeg, int* __restrict__ csr,
                       int* __restrict__ csr0,
                       const uint4* __restrict__ xb, uint4* __restrict__ g0,
                       int N, int E, int K, int cap) {
    __shared__ int gsc[KMAX];
    __shared__ int cnt[NB];
    __shared__ int stmp[NB];
    __shared__ int cur[NB];
    __shared__ float sdinv[NB];
    const int b = blockIdx.x;
    const int tid = threadIdx.x;        // blockDim = 512

    if (b == 0 && tid < 8)               // zero row N of g0
        g0[((size_t)N << 3) + tid] = make_uint4(0, 0, 0, 0);

    int gv = (tid < K) ? gcursor[tid] : 0;
    gsc[tid] = gv;
    __syncthreads();
    for (int o = 1; o < KMAX; o <<= 1) {
        int t = (tid >= o) ? gsc[tid - o] : 0;
        __syncthreads();
        gsc[tid] += t;
        __syncthreads();
    }
    const int ecnt = gcursor[b];
    const int base = gsc[b] - ecnt;     // inclusive - own = exclusive
    const unsigned* bp = pairs + (size_t)b * cap;

    if (tid < NB) cnt[tid] = 0;
    __syncthreads();
    for (int i = tid; i < ecnt; i += 512)
        atomicAdd(&cnt[bp[i] >> 23], 1);
    __syncthreads();
    int v = (tid < NB) ? cnt[tid] : 0;
    if (tid < NB) stmp[tid] = v;
    __syncthreads();
    for (int o = 1; o < NB; o <<= 1) {
        int t = (tid >= o && tid < NB) ? stmp[tid - o] : 0;
        __syncthreads();
        if (tid < NB) stmp[tid] += t;
        __syncthreads();
    }
    int node = (b << BSHIFT) + tid;
    if (tid < NB) {
        int abs0 = base + stmp[tid] - v;            // exclusive, absolute
        cur[tid] = abs0;
        float d = fmaxf((float)v, 1.0f);
        sdinv[tid] = rsqrtf(d);
        if (node < N) {
            rp[node] = abs0;
            dinv2[node] = 1.0f / d;
            rdeg[node]  = sqrtf(d);
        }
    }
    if (b == K - 1 && tid == 0) rp[N] = E;
    __syncthreads();
    for (int i = tid; i < ecnt; i += 512) {
        unsigned p = bp[i];
        int pos = atomicAdd(&cur[p >> 23], 1);      // absolute csr index
        csr[pos] = (int)(p & 0x7FFFFFu);
    }
    __syncthreads();                                 // csr of this bucket done
    // csr0: first 8 slots per node, padded with N (zero row)
    if (tid < NB && node < N) {
        int abs0 = base + stmp[tid] - v;
        int4 q0, q1;
        q0.x = (0 < v) ? csr[abs0 + 0] : N;
        q0.y = (1 < v) ? csr[abs0 + 1] : N;
        q0.z = (2 < v) ? csr[abs0 + 2] : N;
        q0.w = (3 < v) ? csr[abs0 + 3] : N;
        q1.x = (4 < v) ? csr[abs0 + 4] : N;
        q1.y = (5 < v) ? csr[abs0 + 5] : N;
        q1.z = (6 < v) ? csr[abs0 + 6] : N;
        q1.w = (7 < v) ? csr[abs0 + 7] : N;
        *(int4*)(csr0 + ((size_t)node << 3))     = q0;
        *(int4*)(csr0 + ((size_t)node << 3) + 4) = q1;
    }
    // fused g0 = f16(dinv * x) for this bucket's nodes (streaming 32KB)
    const int nbase = b << BSHIFT;
    const int qmax = min(NB, N - nbase) << 3;       // 8 uint4 per node
    const uint4* xbp = xb + ((size_t)nbase << 3);
    uint4* g0p = g0 + ((size_t)nbase << 3);
    for (int q = tid; q < qmax; q += 512) {
        float di = sdinv[q >> 3];
        uint4 xv = xbp[q];
        uint4 o;
        o.x = pack2h(di * hlo(xv.x), di * hhi(xv.x));
        o.y = pack2h(di * hlo(xv.y), di * hhi(xv.y));
        o.z = pack2h(di * hlo(xv.z), di * hhi(xv.z));
        o.w = pack2h(di * hlo(xv.w), di * hhi(xv.w));
        g0p[q] = o;
    }
}

// TWO nodes per wave, f16 feature tables (128B rows), depth-2 software
// pipeline. Lane l: half = l>>5, r = (l>>3)&3, c = l&7.
// First-iteration row indices come from csr0 (no rp dependency); epilogue
// node-addressed loads are hoisted to the prologue under the r==0 mask.
// Packed v_pk_add_f16 accumulate; OOB slots gather zero row n.
// !LAST epilogue: gout[d] = f16(gin[d] - dinv2[d]*acc)  (+ zero row N)
//  LAST epilogue: h[d] = t0*xb[d] + rdeg[d]*(t1*g1+t2*g2+t3*gin+t4*g4),
//                 g4 = gin[d] - dinv2[d]*acc computed in-register.
template <bool LAST>
__global__ void k_gather(const int* __restrict__ rp, const int* __restrict__ csr,
                         const int* __restrict__ csr0,
                         const unsigned short* __restrict__ gin,
                         const float* __restrict__ dinv2,
                         unsigned short* __restrict__ gout,
                         const unsigned short* __restrict__ xb,
                         const unsigned short* __restrict__ g1t,
                         const unsigned short* __restrict__ g2t,
                         const float* __restrict__ rdeg,
                         float* __restrict__ h, int n,
                         float t0, float t1, float t2, float t3, float t4) {
    if (!LAST && blockIdx.x == 0 && threadIdx.x < 8)   // zero row N of gout
        *(((uint4*)(gout + ((size_t)n << 6))) + threadIdx.x) = make_uint4(0, 0, 0, 0);

    int wid = (blockIdx.x * blockDim.x + threadIdx.x) >> 6;
    int lane = threadIdx.x & 63;
    int half = lane >> 5;
    int r = (lane >> 3) & 3;
    int c = lane & 7;
    int node = wid * 2 + half;
    if (wid * 2 >= n) return;
    bool valid = node < n;

    // first-iteration row indices: independent of rp (breaks the chain)
    int s1 = n, s2 = n;
    if (valid) {
        s1 = csr0[((size_t)node << 3) + r];
        s2 = csr0[((size_t)node << 3) + r + 4];
    }
    int beg = valid ? rp[node] : 0;
    int end = valid ? rp[node + 1] : 0;

    // hoisted epilogue loads (node-addressed, exec-masked to 16 lanes)
    const bool ep = (r == 0) && valid;
    size_t off = ((size_t)node << 6) + (c << 3);
    uint4 rr = make_uint4(0, 0, 0, 0);
    float d2 = 0.f, rd = 0.f;
    nv4u xv = {0u, 0u, 0u, 0u}, aa = {0u, 0u, 0u, 0u}, bb = {0u, 0u, 0u, 0u};
    if (ep) {
        rr = *(const uint4*)(gin + off);
        d2 = dinv2[node];
        if (LAST) {
            xv = __builtin_nontemporal_load((const nv4u*)(xb + off));
            aa = __builtin_nontemporal_load((const nv4u*)(g1t + off));
            bb = __builtin_nontemporal_load((const nv4u*)(g2t + off));
            rd = rdeg[node];
        }
    }

    int len = end - beg;
    int olen = __shfl_xor(len, 32, 64);
    int mlen = (len > olen) ? len : olen;   // pair max -> uniform trip count

    unsigned acc[4] = {0u, 0u, 0u, 0u};     // packed f16 pairs

    // pipeline state: current rows (in flight), next row indices
    uint4 rc1 = *(const uint4*)(gin + ((size_t)s1 << 6) + (c << 3));
    uint4 rc2 = *(const uint4*)(gin + ((size_t)s2 << 6) + (c << 3));
    int sn1 = n, sn2 = n;
    {
        int j1b = beg + 8 + r, j2b = j1b + 4;
        bool vb = 8 < mlen;
        bool b1 = vb && (j1b < end), b2 = vb && (j2b < end);
        sn1 = csr[b1 ? j1b : 0]; sn1 = b1 ? sn1 : n;
        sn2 = csr[b2 ? j2b : 0]; sn2 = b2 ? sn2 : n;
    }
    for (int i = 0; i < mlen; i += 8) {
        // issue NEXT iteration's rows (independent of rc1/rc2 wait)
        uint4 rn1 = *(const uint4*)(gin + ((size_t)sn1 << 6) + (c << 3));
        uint4 rn2 = *(const uint4*)(gin + ((size_t)sn2 << 6) + (c << 3));
        // prefetch csr two iterations ahead
        int j1n = beg + i + 16 + r, j2n = j1n + 4;
        bool vn = (i + 16) < mlen;
        bool t1c = vn && (j1n < end), t2c = vn && (j2n < end);
        int st1 = csr[t1c ? j1n : 0]; st1 = t1c ? st1 : n;
        int st2 = csr[t2c ? j2n : 0]; st2 = t2c ? st2 : n;
        // accumulate CURRENT rows (packed f16)
        acc[0] = padd2(acc[0], rc1.x); acc[1] = padd2(acc[1], rc1.y);
        acc[2] = padd2(acc[2], rc1.z); acc[3] = padd2(acc[3], rc1.w);
        acc[0] = padd2(acc[0], rc2.x); acc[1] = padd2(acc[1], rc2.y);
        acc[2] = padd2(acc[2], rc2.z); acc[3] = padd2(acc[3], rc2.w);
        // rotate pipeline
        rc1 = rn1; rc2 = rn2;
        sn1 = st1; sn2 = st2;
    }
    #pragma unroll
    for (int m = 8; m <= 16; m <<= 1) {
        #pragma unroll
        for (int i = 0; i < 4; ++i)
            acc[i] = padd2(acc[i], __shfl_xor(acc[i], m, 64));
    }

    if (ep) {                                // lanes 0..7 and 32..39
        float v[8];
        v[0] = hlo(rr.x) - d2 * hlo(acc[0]); v[1] = hhi(rr.x) - d2 * hhi(acc[0]);
        v[2] = hlo(rr.y) - d2 * hlo(acc[1]); v[3] = hhi(rr.y) - d2 * hhi(acc[1]);
        v[4] = hlo(rr.z) - d2 * hlo(acc[2]); v[5] = hhi(rr.z) - d2 * hhi(acc[2]);
        v[6] = hlo(rr.w) - d2 * hlo(acc[3]); v[7] = hhi(rr.w) - d2 * hhi(acc[3]);
        if (!LAST) {
            nv4u o;
            o.x = pack2h(v[0], v[1]);
            o.y = pack2h(v[2], v[3]);
            o.z = pack2h(v[4], v[5]);
            o.w = pack2h(v[6], v[7]);
            __builtin_nontemporal_store(o, (nv4u*)(gout + off));
        } else {
            float s1f = rd * t1, s2f = rd * t2, s3f = rd * t3, s4f = rd * t4;
            nv4f h0, h1;
            h0.x = t0 * hlo(xv.x) + s1f * hlo(aa.x) + s2f * hlo(bb.x) + s3f * hlo(rr.x) + s4f * v[0];
            h0.y = t0 * hhi(xv.x) + s1f * hhi(aa.x) + s2f * hhi(bb.x) + s3f * hhi(rr.x) + s4f * v[1];
            h0.z = t0 * hlo(xv.y) + s1f * hlo(aa.y) + s2f * hlo(bb.y) + s3f * hlo(rr.y) + s4f * v[2];
            h0.w = t0 * hhi(xv.y) + s1f * hhi(aa.y) + s2f * hhi(bb.y) + s3f * hhi(rr.y) + s4f * v[3];
            h1.x = t0 * hlo(xv.z) + s1f * hlo(aa.z) + s2f * hlo(bb.z) + s3f * hlo(rr.z) + s4f * v[4];
            h1.y = t0 * hhi(xv.z) + s1f * hhi(aa.z) + s2f * hhi(bb.z) + s3f * hhi(rr.z) + s4f * v[5];
            h1.z = t0 * hlo(xv.w) + s1f * hlo(aa.w) + s2f * hlo(bb.w) + s3f * hlo(rr.w) + s4f * v[6];
            h1.w = t0 * hhi(xv.w) + s1f * hhi(aa.w) + s2f * hhi(bb.w) + s3f * hhi(rr.w) + s4f * v[7];
            __builtin_nontemporal_store(h0, (nv4f*)(h + off));
            __builtin_nontemporal_store(h1, (nv4f*)(h + off + 4));
        }
    }
}

extern "C" void kernel_launch(void* const* d_in, const int* in_sizes, int n_in,
                              void* d_out, int out_size, void* d_ws, size_t ws_size,
                              hipStream_t stream) {
    const float* x  = (const float*)d_in[0];
    const int*   ei = (const int*)d_in[1];   // edge_index [2, E] row-major
    const int N = in_sizes[0] / kF;
    const int E = in_sizes[1] / 2;
    const int* src = ei;
    const int* dst = ei + E;
    float* h = (float*)d_out;

    const int K = (N + NB - 1) >> BSHIFT;         // 391 buckets (K <= KMAX)
    const int cap = 2 * ((E + K - 1) / K);        // per-bucket capacity

    // workspace (~76 MB): gcursor | rp | dinv2 | rdeg | csr | csr0 | xb |
    // g0 | g1 (aliases pairs; pairs dead after binB) | g2 | g3
    char* ws = (char*)d_ws;
    size_t off = 0;
    auto carve = [&](size_t bytes) {
        void* p = ws + off;
        off = (off + bytes + 511) & ~(size_t)511;
        return p;
    };
    size_t gbytes = (size_t)(N + 1) * kF * 2;
    int*            gcursor = (int*)carve((size_t)KMAX * 4);
    int*            rp      = (int*)carve((size_t)(N + 1) * 4);
    float*          dinv2   = (float*)carve((size_t)N * 4);
    float*          rdeg    = (float*)carve((size_t)N * 4);
    int*            csr     = (int*)carve((size_t)E * 4);
    int*            csr0    = (int*)carve((size_t)N * 8 * 4);
    unsigned short* xb      = (unsigned short*)carve((size_t)N * kF * 2);
    unsigned short* g0      = (unsigned short*)carve(gbytes);
    size_t pbytes = (size_t)K * cap * 4;
    unsigned short* g1      = (unsigned short*)carve(gbytes > pbytes ? gbytes : pbytes);
    unsigned short* g2      = (unsigned short*)carve(gbytes);
    unsigned short* g3      = (unsigned short*)carve(gbytes);
    unsigned*       pairs   = (unsigned*)g1;       // alias (dead after binB)

    const float theta[5] = {0.6f, -0.4f, 0.3f, -0.2f, 0.1f};
    const int n8 = N * kF / 8;

    // ---- CSR build (multisplit) with fused x->f16 convert and g0 ----
    hipMemsetAsync(gcursor, 0, (size_t)KMAX * 4, stream);
    k_binA<<<(E + TILEA - 1) / TILEA, 512, 0, stream>>>(src, dst, pairs, gcursor,
                                                        (const float4*)x, (uint4*)xb,
                                                        n8, E, K, cap);
    k_binB<<<K, 512, 0, stream>>>(pairs, gcursor, rp, dinv2, rdeg, csr, csr0,
                                  (const uint4*)xb, (uint4*)g0, N, E, K, cap);

    // ---- 4 gather passes; pass 4 fuses the h-combine epilogue ----
    const int nwaves = (N + 1) / 2;                // 2 nodes per wave
    const int gblocks = (nwaves + 3) / 4;          // 4 waves per 256-thread block
    k_gather<false><<<gblocks, 256, 0, stream>>>(rp, csr, csr0, g0, dinv2, g1,
                                                 nullptr, nullptr, nullptr, nullptr,
                                                 nullptr, N, 0, 0, 0, 0, 0);
    k_gather<false><<<gblocks, 256, 0, stream>>>(rp, csr, csr0, g1, dinv2, g2,
                                                 nullptr, nullptr, nullptr, nullptr,
                                                 nullptr, N, 0, 0, 0, 0, 0);
    k_gather<false><<<gblocks, 256, 0, stream>>>(rp, csr, csr0, g2, dinv2, g3,
                                                 nullptr, nullptr, nullptr, nullptr,
                                                 nullptr, N, 0, 0, 0, 0, 0);
    k_gather<true><<<gblocks, 256, 0, stream>>>(rp, csr, csr0, g3, dinv2, nullptr,
                                                xb, g1, g2, rdeg, h, N,
                                                theta[0], theta[1], theta[2],
                                                theta[3], theta[4]);
}

// Round 9
// 237.346 us; speedup vs baseline: 2.0944x; 1.0017x over previous
//
#include <hip/hip_runtime.h>
#include <hip/hip_fp16.h>

// PolyConv: h = sum_k theta[k] * L_sym^k x,  L_sym = I - D^{-1/2} A D^{-1/2}
// N=100000 nodes, E=1600000 edges, F=64 features, 5 theta terms.
//
// Round 23: build rebalance. binA = pure multisplit (TILEA 4096, 30KB LDS
// -> ~4x resident blocks vs r22's 54KB/8192); the x->f16 convert moves to
// binB, which now reads fp32 x once and writes BOTH xb and g0 (g0 scaled
// by dinv, converted straight from fp32). Gathers unchanged from r21/r22
// (csr0 prologue + hoisted epilogue; ~near their BW floor).

constexpr int kF = 64;
constexpr int BSHIFT = 8;             // bucket = dst >> 8  (256 nodes/bucket)
constexpr int NB = 1 << BSHIFT;       // 256 nodes per bucket
constexpr int TILEA = 4096;           // edges per binA block (8/thread)
constexpr int KMAX = 512;             // array bound for K (=391)

typedef unsigned nv4u __attribute__((ext_vector_type(4)));   // nontemporal-safe
typedef float    nv4f __attribute__((ext_vector_type(4)));

static __device__ __forceinline__ float hlo(unsigned u) {        // low f16 -> f32
    return __half2float(__ushort_as_half((unsigned short)(u & 0xffffu)));
}
static __device__ __forceinline__ float hhi(unsigned u) {        // high f16 -> f32
    return __half2float(__ushort_as_half((unsigned short)(u >> 16)));
}
static __device__ __forceinline__ unsigned pack2h(float a, float b) { // RNE
    return (unsigned)__half_as_ushort(__float2half_rn(a)) |
           ((unsigned)__half_as_ushort(__float2half_rn(b)) << 16);
}
static __device__ __forceinline__ unsigned padd2(unsigned a, unsigned b) {
    __half2 ha = *reinterpret_cast<__half2*>(&a);
    __half2 hb = *reinterpret_cast<__half2*>(&b);
    __half2 hc = __hadd2(ha, hb);                 // v_pk_add_f16
    return *reinterpret_cast<unsigned*>(&hc);
}

// Phase A: pure edge multisplit into K buckets. Per 4096-edge tile: LDS
// histogram -> KMAX scan -> LDS counting-sort -> global reserve ->
// bucket-ordered coalesced write-out.
__global__ void k_binA(const int* __restrict__ src, const int* __restrict__ dst,
                       unsigned* __restrict__ pairs, int* __restrict__ gcursor,
                       int E, int K, int cap) {
    __shared__ unsigned stage[TILEA];        // 16 KB bucket-sorted entries
    __shared__ unsigned short stageB[TILEA]; // 8 KB bucket id per slot
    __shared__ int hist[KMAX];               // counts -> cursors
    __shared__ int lb[KMAX];                 // local exclusive base
    __shared__ int gb[KMAX];                 // global base per bucket
    const int tid = threadIdx.x;        // blockDim = 512
    const long long tb = (long long)blockIdx.x * TILEA;
    const int tcount = (int)min((long long)TILEA, (long long)E - tb);

    hist[tid] = 0;
    __syncthreads();
    int dc[8], sc[8];
    #pragma unroll
    for (int k = 0; k < 8; ++k) {
        int i = tid + k * 512;
        if (i < tcount) {
            dc[k] = dst[tb + i];
            sc[k] = src[tb + i];
            atomicAdd(&hist[dc[k] >> BSHIFT], 1);
        } else {
            dc[k] = -1;
        }
    }
    __syncthreads();
    const int cnt = hist[tid];
    lb[tid] = cnt;
    __syncthreads();
    for (int o = 1; o < KMAX; o <<= 1) {
        int t = (tid >= o) ? lb[tid - o] : 0;
        __syncthreads();
        lb[tid] += t;
        __syncthreads();
    }
    const int excl = lb[tid] - cnt;          // local exclusive base
    __syncthreads();
    lb[tid] = excl;
    gb[tid] = (tid < K && cnt > 0) ? atomicAdd(&gcursor[tid], cnt) : 0;
    hist[tid] = excl;                        // reuse as LDS scatter cursor
    __syncthreads();
    #pragma unroll
    for (int k = 0; k < 8; ++k) {
        if (dc[k] >= 0) {
            int d = dc[k];
            int b = d >> BSHIFT;
            int pos = atomicAdd(&hist[b], 1);
            stage[pos]  = ((unsigned)(d & (NB - 1)) << 23) | (unsigned)sc[k];
            stageB[pos] = (unsigned short)b;
        }
    }
    __syncthreads();
    // bucket-ordered write-out: consecutive j -> consecutive addresses
    for (int j = tid; j < tcount; j += 512) {
        int b = stageB[j];
        pairs[(size_t)b * cap + gb[b] + (j - lb[b])] = stage[j];
    }
}

// Phase B: one block (512 thr) per bucket of 256 nodes. In-kernel gbase
// scan, per-node counts -> LDS scan -> rp/dinv2/rdeg, scatter plain src
// ints to csr via absolute LDS cursors, write csr0 (first 8 slots per
// node, padded with N), then convert own bucket's x (fp32) -> xb (f16)
// AND g0 = f16(dinv * x). Zeroes g0's row N (OOB gather slots).
__global__ void k_binB(const unsigned* __restrict__ pairs, const int* __restrict__ gcursor,
                       int* __restrict__ rp, float* __restrict__ dinv2,
                       float* __restrict__ rdeg, int* __restrict__ csr,
                       int* __restrict__ csr0,
                       const float4* __restrict__ x4,
                       uint4* __restrict__ xb4, uint4* __restrict__ g0,
                       int N, int E, int K, int cap) {
    __shared__ int gsc[KMAX];
    __shared__ int cnt[NB];
    __shared__ int stmp[NB];
    __shared__ int cur[NB];
    __shared__ float sdinv[NB];
    const int b = blockIdx.x;
    const int tid = threadIdx.x;        // blockDim = 512

    if (b == 0 && tid < 8)               // zero row N of g0
        g0[((size_t)N << 3) + tid] = make_uint4(0, 0, 0, 0);

    int gv = (tid < K) ? gcursor[tid] : 0;
    gsc[tid] = gv;
    __syncthreads();
    for (int o = 1; o < KMAX; o <<= 1) {
        int t = (tid >= o) ? gsc[tid - o] : 0;
        __syncthreads();
        gsc[tid] += t;
        __syncthreads();
    }
    const int ecnt = gcursor[b];
    const int base = gsc[b] - ecnt;     // inclusive - own = exclusive
    const unsigned* bp = pairs + (size_t)b * cap;

    if (tid < NB) cnt[tid] = 0;
    __syncthreads();
    for (int i = tid; i < ecnt; i += 512)
        atomicAdd(&cnt[bp[i] >> 23], 1);
    __syncthreads();
    int v = (tid < NB) ? cnt[tid] : 0;
    if (tid < NB) stmp[tid] = v;
    __syncthreads();
    for (int o = 1; o < NB; o <<= 1) {
        int t = (tid >= o && tid < NB) ? stmp[tid - o] : 0;
        __syncthreads();
        if (tid < NB) stmp[tid] += t;
        __syncthreads();
    }
    int node = (b << BSHIFT) + tid;
    if (tid < NB) {
        int abs0 = base + stmp[tid] - v;            // exclusive, absolute
        cur[tid] = abs0;
        float d = fmaxf((float)v, 1.0f);
        sdinv[tid] = rsqrtf(d);
        if (node < N) {
            rp[node] = abs0;
            dinv2[node] = 1.0f / d;
            rdeg[node]  = sqrtf(d);
        }
    }
    if (b == K - 1 && tid == 0) rp[N] = E;
    __syncthreads();
    for (int i = tid; i < ecnt; i += 512) {
        unsigned p = bp[i];
        int pos = atomicAdd(&cur[p >> 23], 1);      // absolute csr index
        csr[pos] = (int)(p & 0x7FFFFFu);
    }
    __syncthreads();                                 // csr of this bucket done
    // csr0: first 8 slots per node, padded with N (zero row)
    if (tid < NB && node < N) {
        int abs0 = base + stmp[tid] - v;
        int4 q0, q1;
        q0.x = (0 < v) ? csr[abs0 + 0] : N;
        q0.y = (1 < v) ? csr[abs0 + 1] : N;
        q0.z = (2 < v) ? csr[abs0 + 2] : N;
        q0.w = (3 < v) ? csr[abs0 + 3] : N;
        q1.x = (4 < v) ? csr[abs0 + 4] : N;
        q1.y = (5 < v) ? csr[abs0 + 5] : N;
        q1.z = (6 < v) ? csr[abs0 + 6] : N;
        q1.w = (7 < v) ? csr[abs0 + 7] : N;
        *(int4*)(csr0 + ((size_t)node << 3))     = q0;
        *(int4*)(csr0 + ((size_t)node << 3) + 4) = q1;
    }
    // fused convert for this bucket's nodes: x (fp32) -> xb, g0 = dinv*x
    const int nbase = b << BSHIFT;
    const int qmax = min(NB, N - nbase) << 3;       // 8 uint4 per node
    uint4* g0p = g0 + ((size_t)nbase << 3);
    for (int q = tid; q < qmax; q += 512) {
        int gq = ((nbase + (q >> 3)) << 3) + (q & 7);   // global uint4 idx
        float4 a = x4[2 * gq];
        float4 bb = x4[2 * gq + 1];
        uint4 xo;
        xo.x = pack2h(a.x, a.y);
        xo.y = pack2h(a.z, a.w);
        xo.z = pack2h(bb.x, bb.y);
        xo.w = pack2h(bb.z, bb.w);
        xb4[gq] = xo;
        float di = sdinv[q >> 3];
        uint4 go;
        go.x = pack2h(di * a.x, di * a.y);
        go.y = pack2h(di * a.z, di * a.w);
        go.z = pack2h(di * bb.x, di * bb.y);
        go.w = pack2h(di * bb.z, di * bb.w);
        g0p[q] = go;
    }
}

// TWO nodes per wave, f16 feature tables (128B rows), depth-2 software
// pipeline. Lane l: half = l>>5, r = (l>>3)&3, c = l&7.
// First-iteration row indices come from csr0 (no rp dependency); epilogue
// node-addressed loads are hoisted to the prologue under the r==0 mask.
// Packed v_pk_add_f16 accumulate; OOB slots gather zero row n.
// !LAST epilogue: gout[d] = f16(gin[d] - dinv2[d]*acc)  (+ zero row N)
//  LAST epilogue: h[d] = t0*xb[d] + rdeg[d]*(t1*g1+t2*g2+t3*gin+t4*g4),
//                 g4 = gin[d] - dinv2[d]*acc computed in-register.
template <bool LAST>
__global__ void k_gather(const int* __restrict__ rp, const int* __restrict__ csr,
                         const int* __restrict__ csr0,
                         const unsigned short* __restrict__ gin,
                         const float* __restrict__ dinv2,
                         unsigned short* __restrict__ gout,
                         const unsigned short* __restrict__ xb,
                         const unsigned short* __restrict__ g1t,
                         const unsigned short* __restrict__ g2t,
                         const float* __restrict__ rdeg,
                         float* __restrict__ h, int n,
                         float t0, float t1, float t2, float t3, float t4) {
    if (!LAST && blockIdx.x == 0 && threadIdx.x < 8)   // zero row N of gout
        *(((uint4*)(gout + ((size_t)n << 6))) + threadIdx.x) = make_uint4(0, 0, 0, 0);

    int wid = (blockIdx.x * blockDim.x + threadIdx.x) >> 6;
    int lane = threadIdx.x & 63;
    int half = lane >> 5;
    int r = (lane >> 3) & 3;
    int c = lane & 7;
    int node = wid * 2 + half;
    if (wid * 2 >= n) return;
    bool valid = node < n;

    // first-iteration row indices: independent of rp (breaks the chain)
    int s1 = n, s2 = n;
    if (valid) {
        s1 = csr0[((size_t)node << 3) + r];
        s2 = csr0[((size_t)node << 3) + r + 4];
    }
    int beg = valid ? rp[node] : 0;
    int end = valid ? rp[node + 1] : 0;

    // hoisted epilogue loads (node-addressed, exec-masked to 16 lanes)
    const bool ep = (r == 0) && valid;
    size_t off = ((size_t)node << 6) + (c << 3);
    uint4 rr = make_uint4(0, 0, 0, 0);
    float d2 = 0.f, rd = 0.f;
    nv4u xv = {0u, 0u, 0u, 0u}, aa = {0u, 0u, 0u, 0u}, bb = {0u, 0u, 0u, 0u};
    if (ep) {
        rr = *(const uint4*)(gin + off);
        d2 = dinv2[node];
        if (LAST) {
            xv = __builtin_nontemporal_load((const nv4u*)(xb + off));
            aa = __builtin_nontemporal_load((const nv4u*)(g1t + off));
            bb = __builtin_nontemporal_load((const nv4u*)(g2t + off));
            rd = rdeg[node];
        }
    }

    int len = end - beg;
    int olen = __shfl_xor(len, 32, 64);
    int mlen = (len > olen) ? len : olen;   // pair max -> uniform trip count

    unsigned acc[4] = {0u, 0u, 0u, 0u};     // packed f16 pairs

    // pipeline state: current rows (in flight), next row indices
    uint4 rc1 = *(const uint4*)(gin + ((size_t)s1 << 6) + (c << 3));
    uint4 rc2 = *(const uint4*)(gin + ((size_t)s2 << 6) + (c << 3));
    int sn1 = n, sn2 = n;
    {
        int j1b = beg + 8 + r, j2b = j1b + 4;
        bool vb = 8 < mlen;
        bool b1 = vb && (j1b < end), b2 = vb && (j2b < end);
        sn1 = csr[b1 ? j1b : 0]; sn1 = b1 ? sn1 : n;
        sn2 = csr[b2 ? j2b : 0]; sn2 = b2 ? sn2 : n;
    }
    for (int i = 0; i < mlen; i += 8) {
        // issue NEXT iteration's rows (independent of rc1/rc2 wait)
        uint4 rn1 = *(const uint4*)(gin + ((size_t)sn1 << 6) + (c << 3));
        uint4 rn2 = *(const uint4*)(gin + ((size_t)sn2 << 6) + (c << 3));
        // prefetch csr two iterations ahead
        int j1n = beg + i + 16 + r, j2n = j1n + 4;
        bool vn = (i + 16) < mlen;
        bool t1c = vn && (j1n < end), t2c = vn && (j2n < end);
        int st1 = csr[t1c ? j1n : 0]; st1 = t1c ? st1 : n;
        int st2 = csr[t2c ? j2n : 0]; st2 = t2c ? st2 : n;
        // accumulate CURRENT rows (packed f16)
        acc[0] = padd2(acc[0], rc1.x); acc[1] = padd2(acc[1], rc1.y);
        acc[2] = padd2(acc[2], rc1.z); acc[3] = padd2(acc[3], rc1.w);
        acc[0] = padd2(acc[0], rc2.x); acc[1] = padd2(acc[1], rc2.y);
        acc[2] = padd2(acc[2], rc2.z); acc[3] = padd2(acc[3], rc2.w);
        // rotate pipeline
        rc1 = rn1; rc2 = rn2;
        sn1 = st1; sn2 = st2;
    }
    #pragma unroll
    for (int m = 8; m <= 16; m <<= 1) {
        #pragma unroll
        for (int i = 0; i < 4; ++i)
            acc[i] = padd2(acc[i], __shfl_xor(acc[i], m, 64));
    }

    if (ep) {                                // lanes 0..7 and 32..39
        float v[8];
        v[0] = hlo(rr.x) - d2 * hlo(acc[0]); v[1] = hhi(rr.x) - d2 * hhi(acc[0]);
        v[2] = hlo(rr.y) - d2 * hlo(acc[1]); v[3] = hhi(rr.y) - d2 * hhi(acc[1]);
        v[4] = hlo(rr.z) - d2 * hlo(acc[2]); v[5] = hhi(rr.z) - d2 * hhi(acc[2]);
        v[6] = hlo(rr.w) - d2 * hlo(acc[3]); v[7] = hhi(rr.w) - d2 * hhi(acc[3]);
        if (!LAST) {
            nv4u o;
            o.x = pack2h(v[0], v[1]);
            o.y = pack2h(v[2], v[3]);
            o.z = pack2h(v[4], v[5]);
            o.w = pack2h(v[6], v[7]);
            __builtin_nontemporal_store(o, (nv4u*)(gout + off));
        } else {
            float s1f = rd * t1, s2f = rd * t2, s3f = rd * t3, s4f = rd * t4;
            nv4f h0, h1;
            h0.x = t0 * hlo(xv.x) + s1f * hlo(aa.x) + s2f * hlo(bb.x) + s3f * hlo(rr.x) + s4f * v[0];
            h0.y = t0 * hhi(xv.x) + s1f * hhi(aa.x) + s2f * hhi(bb.x) + s3f * hhi(rr.x) + s4f * v[1];
            h0.z = t0 * hlo(xv.y) + s1f * hlo(aa.y) + s2f * hlo(bb.y) + s3f * hlo(rr.y) + s4f * v[2];
            h0.w = t0 * hhi(xv.y) + s1f * hhi(aa.y) + s2f * hhi(bb.y) + s3f * hhi(rr.y) + s4f * v[3];
            h1.x = t0 * hlo(xv.z) + s1f * hlo(aa.z) + s2f * hlo(bb.z) + s3f * hlo(rr.z) + s4f * v[4];
            h1.y = t0 * hhi(xv.z) + s1f * hhi(aa.z) + s2f * hhi(bb.z) + s3f * hhi(rr.z) + s4f * v[5];
            h1.z = t0 * hlo(xv.w) + s1f * hlo(aa.w) + s2f * hlo(bb.w) + s3f * hlo(rr.w) + s4f * v[6];
            h1.w = t0 * hhi(xv.w) + s1f * hhi(aa.w) + s2f * hhi(bb.w) + s3f * hhi(rr.w) + s4f * v[7];
            __builtin_nontemporal_store(h0, (nv4f*)(h + off));
            __builtin_nontemporal_store(h1, (nv4f*)(h + off + 4));
        }
    }
}

extern "C" void kernel_launch(void* const* d_in, const int* in_sizes, int n_in,
                              void* d_out, int out_size, void* d_ws, size_t ws_size,
                              hipStream_t stream) {
    const float* x  = (const float*)d_in[0];
    const int*   ei = (const int*)d_in[1];   // edge_index [2, E] row-major
    const int N = in_sizes[0] / kF;
    const int E = in_sizes[1] / 2;
    const int* src = ei;
    const int* dst = ei + E;
    float* h = (float*)d_out;

    const int K = (N + NB - 1) >> BSHIFT;         // 391 buckets (K <= KMAX)
    const int cap = 2 * ((E + K - 1) / K);        // per-bucket capacity

    // workspace (~76 MB): gcursor | rp | dinv2 | rdeg | csr | csr0 | xb |
    // g0 | g1 (aliases pairs; pairs dead after binB) | g2 | g3
    char* ws = (char*)d_ws;
    size_t off = 0;
    auto carve = [&](size_t bytes) {
        void* p = ws + off;
        off = (off + bytes + 511) & ~(size_t)511;
        return p;
    };
    size_t gbytes = (size_t)(N + 1) * kF * 2;
    int*            gcursor = (int*)carve((size_t)KMAX * 4);
    int*            rp      = (int*)carve((size_t)(N + 1) * 4);
    float*          dinv2   = (float*)carve((size_t)N * 4);
    float*          rdeg    = (float*)carve((size_t)N * 4);
    int*            csr     = (int*)carve((size_t)E * 4);
    int*            csr0    = (int*)carve((size_t)N * 8 * 4);
    unsigned short* xb      = (unsigned short*)carve((size_t)N * kF * 2);
    unsigned short* g0      = (unsigned short*)carve(gbytes);
    size_t pbytes = (size_t)K * cap * 4;
    unsigned short* g1      = (unsigned short*)carve(gbytes > pbytes ? gbytes : pbytes);
    unsigned short* g2      = (unsigned short*)carve(gbytes);
    unsigned short* g3      = (unsigned short*)carve(gbytes);
    unsigned*       pairs   = (unsigned*)g1;       // alias (dead after binB)

    const float theta[5] = {0.6f, -0.4f, 0.3f, -0.2f, 0.1f};

    // ---- CSR build (multisplit); binB also does x->xb and g0 ----
    hipMemsetAsync(gcursor, 0, (size_t)KMAX * 4, stream);
    k_binA<<<(E + TILEA - 1) / TILEA, 512, 0, stream>>>(src, dst, pairs, gcursor,
                                                        E, K, cap);
    k_binB<<<K, 512, 0, stream>>>(pairs, gcursor, rp, dinv2, rdeg, csr, csr0,
                                  (const float4*)x, (uint4*)xb, (uint4*)g0,
                                  N, E, K, cap);

    // ---- 4 gather passes; pass 4 fuses the h-combine epilogue ----
    const int nwaves = (N + 1) / 2;                // 2 nodes per wave
    const int gblocks = (nwaves + 3) / 4;          // 4 waves per 256-thread block
    k_gather<false><<<gblocks, 256, 0, stream>>>(rp, csr, csr0, g0, dinv2, g1,
                                                 nullptr, nullptr, nullptr, nullptr,
                                                 nullptr, N, 0, 0, 0, 0, 0);
    k_gather<false><<<gblocks, 256, 0, stream>>>(rp, csr, csr0, g1, dinv2, g2,
                                                 nullptr, nullptr, nullptr, nullptr,
                                                 nullptr, N, 0, 0, 0, 0, 0);
    k_gather<false><<<gblocks, 256, 0, stream>>>(rp, csr, csr0, g2, dinv2, g3,
                                                 nullptr, nullptr, nullptr, nullptr,
                                                 nullptr, N, 0, 0, 0, 0, 0);
    k_gather<true><<<gblocks, 256, 0, stream>>>(rp, csr, csr0, g3, dinv2, nullptr,
                                                xb, g1, g2, rdeg, h, N,
                                                theta[0], theta[1], theta[2],
                                                theta[3], theta[4]);
}